// Round 1
// baseline (1971.933 us; speedup 1.0000x reference)
//
#include <hip/hip_runtime.h>
#include <hip/hip_bf16.h>

// Problem constants (from reference)
constexpr int NN   = 50000;    // nodes
constexpr int NE   = 800000;   // edges (without self loops)
constexpr int ETOT = NE + NN;  // edges + self loops
constexpr int BGR  = 64;       // graphs
constexpr int HID  = 128;
constexpr int HEADS= 4;
constexpr int CDIM = 32;
constexpr int EDIM = 16;
constexpr int NDIM = 8;
constexpr int LAYERS = 3;
constexpr int HALF = 64;       // HID/2
constexpr int NCLS = 6;
constexpr int NAVD = 4;

// d_out layout (flat f32): h[NN*HID], scene[BGR*NCLS], nav[BGR*NAVD], graph[BGR*HID]
constexpr int OUT_SCENE = NN * HID;              // 6,400,000
constexpr int OUT_NAV   = OUT_SCENE + BGR*NCLS;  // 6,400,384
constexpr int OUT_GRAPH = OUT_NAV + BGR*NAVD;    // 6,400,640

// ---------------- mean of edge_attr (sums; divided later) ----------------
__global__ void mean_ea_kernel(const float* __restrict__ ea, float* __restrict__ mean_sum) {
    __shared__ float sdata[256];
    int tid = threadIdx.x;
    float acc = 0.f;
    int stride = gridDim.x * blockDim.x;            // multiple of 16
    for (int i = blockIdx.x * blockDim.x + tid; i < NE * EDIM; i += stride)
        acc += ea[i];
    sdata[tid] = acc;
    __syncthreads();
    // reduce threads with equal tid%16 (offsets are multiples of 16)
    for (int off = 128; off >= 16; off >>= 1) {
        if (tid < off) sdata[tid] += sdata[tid + off];
        __syncthreads();
    }
    if (tid < 16) atomicAdd(&mean_sum[tid], sdata[tid]);
}

// ---------------- per-layer folded attention vectors ----------------
// was[l][k][h] = sum_c W_l[k, h*C+c] * att_src[l,h,c]   (same for wad)
// w_e[l][k][h] = sum_c We_l[k, h*C+c] * att_edge[l,h,c]
// mean_alpha[l][h] = (mean_ea) . w_e[l][:,h]
__global__ void precompute_kernel(const float* __restrict__ lin_W,
                                  const float* __restrict__ lin_edge_W,
                                  const float* __restrict__ att_src,
                                  const float* __restrict__ att_dst,
                                  const float* __restrict__ att_edge,
                                  const float* __restrict__ mean_sum,
                                  float* __restrict__ was, float* __restrict__ wad,
                                  float* __restrict__ w_e, float* __restrict__ mean_alpha) {
    int l = blockIdx.x;
    int t = threadIdx.x;   // 128 threads
    __shared__ float we_s[EDIM * HEADS];
    const float* W  = lin_W     + l * HID * HID;
    const float* We = lin_edge_W+ l * EDIM * HID;
    const float* as = att_src   + l * HEADS * CDIM;
    const float* ad = att_dst   + l * HEADS * CDIM;
    const float* ae = att_edge  + l * HEADS * CDIM;
    #pragma unroll
    for (int h = 0; h < HEADS; h++) {
        float s1 = 0.f, s2 = 0.f;
        #pragma unroll
        for (int c = 0; c < CDIM; c++) {
            float wv = W[t * HID + h * CDIM + c];
            s1 += wv * as[h * CDIM + c];
            s2 += wv * ad[h * CDIM + c];
        }
        was[(l * HID + t) * HEADS + h] = s1;
        wad[(l * HID + t) * HEADS + h] = s2;
    }
    if (t < EDIM) {
        #pragma unroll
        for (int h = 0; h < HEADS; h++) {
            float s = 0.f;
            #pragma unroll
            for (int c = 0; c < CDIM; c++)
                s += We[t * HID + h * CDIM + c] * ae[h * CDIM + c];
            we_s[t * HEADS + h] = s;
            w_e[(l * EDIM + t) * HEADS + h] = s;
        }
    }
    __syncthreads();
    if (t < HEADS) {
        float s = 0.f;
        #pragma unroll
        for (int k = 0; k < EDIM; k++)
            s += (mean_sum[k] * (1.f / (float)NE)) * we_s[k * HEADS + t];
        mean_alpha[l * HEADS + t] = s;
    }
}

// ---------------- initial projection: h = relu(x @ proj_W + proj_b) ----------------
__global__ void proj_kernel(const float* __restrict__ x, const float* __restrict__ pW,
                            const float* __restrict__ pb, float* __restrict__ h) {
    int node = blockIdx.x;
    int t = threadIdx.x;   // 128
    __shared__ float xr[NDIM];
    if (t < NDIM) xr[t] = x[node * NDIM + t];
    __syncthreads();
    float acc = pb[t];
    #pragma unroll
    for (int k = 0; k < NDIM; k++) acc += xr[k] * pW[k * HID + t];
    h[node * HID + t] = fmaxf(acc, 0.f);
}

// ---------------- xh = h @ W ; a_src = h @ was ; a_dst = h @ wad ----------------
__global__ void xh_kernel(const float* __restrict__ hin, const float* __restrict__ W,
                          const float* __restrict__ was, const float* __restrict__ wad,
                          float* __restrict__ xh, float* __restrict__ asrc,
                          float* __restrict__ adst) {
    int node = blockIdx.x;
    int t = threadIdx.x;   // 128
    __shared__ float hr[HID];
    hr[t] = hin[node * HID + t];
    __syncthreads();
    float acc = 0.f;
    #pragma unroll 8
    for (int k = 0; k < HID; k++) acc += hr[k] * W[k * HID + t];
    xh[node * HID + t] = acc;
    if (t < HEADS) {
        float s = 0.f;
        for (int k = 0; k < HID; k++) s += hr[k] * was[k * HEADS + t];
        asrc[node * HEADS + t] = s;
    } else if (t < 2 * HEADS) {
        int h = t - HEADS;
        float s = 0.f;
        for (int k = 0; k < HID; k++) s += hr[k] * wad[k * HEADS + h];
        adst[node * HEADS + h] = s;
    }
}

// ---------------- CSR build ----------------
__global__ void hist_kernel(const int* __restrict__ ei, int* __restrict__ counts) {
    int e = blockIdx.x * blockDim.x + threadIdx.x;
    if (e >= ETOT) return;
    int d = (e < NE) ? ei[NE + e] : (e - NE);
    atomicAdd(&counts[d], 1);
}

__global__ void scan_kernel(const int* __restrict__ counts, int* __restrict__ offsets) {
    __shared__ int sdata[1024];
    __shared__ int carry;
    if (threadIdx.x == 0) carry = 0;
    __syncthreads();
    for (int base = 0; base < NN; base += 1024) {
        int i = base + threadIdx.x;
        int v = (i < NN) ? counts[i] : 0;
        sdata[threadIdx.x] = v;
        __syncthreads();
        for (int off = 1; off < 1024; off <<= 1) {
            int t = 0;
            if (threadIdx.x >= off) t = sdata[threadIdx.x - off];
            __syncthreads();
            sdata[threadIdx.x] += t;
            __syncthreads();
        }
        if (i < NN) offsets[i] = carry + sdata[threadIdx.x] - v;   // exclusive
        __syncthreads();
        if (threadIdx.x == 0) carry += sdata[1023];
        __syncthreads();
    }
}

__global__ void scatter_kernel(const int* __restrict__ ei, const int* __restrict__ offsets,
                               int* __restrict__ fill, int* __restrict__ perm) {
    int e = blockIdx.x * blockDim.x + threadIdx.x;
    if (e >= ETOT) return;
    int d = (e < NE) ? ei[NE + e] : (e - NE);
    int pos = offsets[d] + atomicAdd(&fill[d], 1);
    perm[pos] = e;
}

// ---------------- per-edge raw attention logits (leaky-relu'd) ----------------
__global__ void edge_alpha_kernel(const int* __restrict__ ei, const float* __restrict__ ea,
                                  const float* __restrict__ asrc, const float* __restrict__ adst,
                                  const float* __restrict__ w_e, const float* __restrict__ mean_alpha,
                                  float* __restrict__ alpha) {
    __shared__ float we_s[EDIM * HEADS];
    if (threadIdx.x < EDIM * HEADS) we_s[threadIdx.x] = w_e[threadIdx.x];
    __syncthreads();
    int e = blockIdx.x * blockDim.x + threadIdx.x;
    if (e >= ETOT) return;
    int s, d;
    float e0, e1, e2, e3;
    if (e < NE) {
        s = ei[e];
        d = ei[NE + e];
        const float* er = ea + (size_t)e * EDIM;
        e0 = e1 = e2 = e3 = 0.f;
        #pragma unroll
        for (int k = 0; k < EDIM; k++) {
            float xv = er[k];
            e0 += xv * we_s[k * HEADS + 0];
            e1 += xv * we_s[k * HEADS + 1];
            e2 += xv * we_s[k * HEADS + 2];
            e3 += xv * we_s[k * HEADS + 3];
        }
    } else {
        s = d = e - NE;
        float4 ma = *(const float4*)mean_alpha;
        e0 = ma.x; e1 = ma.y; e2 = ma.z; e3 = ma.w;
    }
    float4 A = *(const float4*)(asrc + s * HEADS);
    float4 D = *(const float4*)(adst + d * HEADS);
    float a0 = A.x + D.x + e0, a1 = A.y + D.y + e1;
    float a2 = A.z + D.z + e2, a3 = A.w + D.w + e3;
    a0 = (a0 > 0.f) ? a0 : 0.2f * a0;
    a1 = (a1 > 0.f) ? a1 : 0.2f * a1;
    a2 = (a2 > 0.f) ? a2 : 0.2f * a2;
    a3 = (a3 > 0.f) ? a3 : 0.2f * a3;
    *(float4*)(alpha + e * HEADS) = make_float4(a0, a1, a2, a3);
}

// ---------------- per-node aggregation + bias + residual + LN + relu ----------------
// One 64-lane wave per node; lane owns channels 2*lane, 2*lane+1; head = lane>>4.
__launch_bounds__(256)
__global__ void aggregate_kernel(const int* __restrict__ ei, const int* __restrict__ perm,
                                 const int* __restrict__ offsets, const int* __restrict__ counts,
                                 const float* __restrict__ alpha, const float* __restrict__ xh,
                                 const float* __restrict__ hres, const float* __restrict__ bias,
                                 const float* __restrict__ lng, const float* __restrict__ lnb,
                                 float* __restrict__ hout) {
    int wid  = threadIdx.x >> 6;
    int lane = threadIdx.x & 63;
    int node = blockIdx.x * 4 + wid;
    if (node >= NN) return;
    int start = offsets[node];
    int deg   = counts[node];
    int head  = lane >> 4;
    int c0    = lane * 2;

    float m = -1e30f;
    for (int j = 0; j < deg; j++) {
        int e = perm[start + j];
        m = fmaxf(m, alpha[e * HEADS + head]);
    }
    float dsum = 0.f, acc0 = 0.f, acc1 = 0.f;
    for (int j = 0; j < deg; j++) {
        int e = perm[start + j];
        float p = __expf(alpha[e * HEADS + head] - m);
        int s = (e < NE) ? ei[e] : (e - NE);
        float2 v = *(const float2*)(xh + s * HID + c0);
        dsum += p;
        acc0 += p * v.x;
        acc1 += p * v.y;
    }
    float inv = 1.f / (dsum + 1e-16f);
    float2 r = *(const float2*)(hres + node * HID + c0);
    float v0 = acc0 * inv + bias[c0]     + r.x;
    float v1 = acc1 * inv + bias[c0 + 1] + r.y;

    // LayerNorm over 128 channels spread 2-per-lane across the wave
    float ssum = v0 + v1;
    #pragma unroll
    for (int off = 32; off > 0; off >>= 1) ssum += __shfl_xor(ssum, off);
    float mu = ssum * (1.f / 128.f);
    float d0 = v0 - mu, d1 = v1 - mu;
    float vs = d0 * d0 + d1 * d1;
    #pragma unroll
    for (int off = 32; off > 0; off >>= 1) vs += __shfl_xor(vs, off);
    float rstd = rsqrtf(vs * (1.f / 128.f) + 1e-5f);
    float y0 = fmaxf(d0 * rstd * lng[c0]     + lnb[c0],     0.f);
    float y1 = fmaxf(d1 * rstd * lng[c0 + 1] + lnb[c0 + 1], 0.f);
    *(float2*)(hout + node * HID + c0) = make_float2(y0, y1);
}

// ---------------- graph mean-pool (sums + counts via atomics) ----------------
__global__ void pool_kernel(const float* __restrict__ h, const int* __restrict__ batch,
                            float* __restrict__ gsum, float* __restrict__ gcnt) {
    int wid  = threadIdx.x >> 6;
    int lane = threadIdx.x & 63;
    int node = blockIdx.x * 4 + wid;
    if (node >= NN) return;
    int b = batch[node];
    int c0 = lane * 2;
    float2 v = *(const float2*)(h + node * HID + c0);
    atomicAdd(&gsum[b * HID + c0],     v.x);
    atomicAdd(&gsum[b * HID + c0 + 1], v.y);
    if (lane == 0) atomicAdd(&gcnt[b], 1.f);
}

// ---------------- graph heads ----------------
__global__ void head_kernel(const float* __restrict__ gsum, const float* __restrict__ gcnt,
                            const float* __restrict__ scW1, const float* __restrict__ scb1,
                            const float* __restrict__ scW2, const float* __restrict__ scb2,
                            const float* __restrict__ nvW1, const float* __restrict__ nvb1,
                            const float* __restrict__ nvW2, const float* __restrict__ nvb2,
                            float* __restrict__ out) {
    int b = blockIdx.x;
    int t = threadIdx.x;   // 128
    __shared__ float gr[HID];
    __shared__ float h1[HALF];
    __shared__ float h2[HALF];
    float cnt = fmaxf(gcnt[b], 1.f);
    float gv = gsum[b * HID + t] / cnt;
    gr[t] = gv;
    out[OUT_GRAPH + b * HID + t] = gv;
    __syncthreads();
    if (t < HALF) {
        float a = scb1[t], n = nvb1[t];
        #pragma unroll 4
        for (int k = 0; k < HID; k++) {
            float g = gr[k];
            a += g * scW1[k * HALF + t];
            n += g * nvW1[k * HALF + t];
        }
        h1[t] = fmaxf(a, 0.f);
        h2[t] = fmaxf(n, 0.f);
    }
    __syncthreads();
    if (t < NCLS) {
        float a = scb2[t];
        #pragma unroll 8
        for (int j = 0; j < HALF; j++) a += h1[j] * scW2[j * NCLS + t];
        out[OUT_SCENE + b * NCLS + t] = a;
    }
    if (t >= 64 && t < 64 + NAVD) {
        int q = t - 64;
        float a = nvb2[q];
        #pragma unroll 8
        for (int j = 0; j < HALF; j++) a += h2[j] * nvW2[j * NAVD + q];
        out[OUT_NAV + b * NAVD + q] = 1.f / (1.f + expf(-a));
    }
}

extern "C" void kernel_launch(void* const* d_in, const int* in_sizes, int n_in,
                              void* d_out, int out_size, void* d_ws, size_t ws_size,
                              hipStream_t stream) {
    const float* x        = (const float*)d_in[0];
    const int*   ei       = (const int*)  d_in[1];
    const float* ea       = (const float*)d_in[2];
    const int*   batch    = (const int*)  d_in[3];
    const float* proj_W   = (const float*)d_in[4];
    const float* proj_b   = (const float*)d_in[5];
    const float* lin_W    = (const float*)d_in[6];
    const float* lin_eW   = (const float*)d_in[7];
    const float* att_src  = (const float*)d_in[8];
    const float* att_dst  = (const float*)d_in[9];
    const float* att_edge = (const float*)d_in[10];
    const float* conv_bias= (const float*)d_in[11];
    const float* ln_g     = (const float*)d_in[12];
    const float* ln_b     = (const float*)d_in[13];
    const float* sc_W1    = (const float*)d_in[14];
    const float* sc_b1    = (const float*)d_in[15];
    const float* sc_W2    = (const float*)d_in[16];
    const float* sc_b2    = (const float*)d_in[17];
    const float* nav_W1   = (const float*)d_in[18];
    const float* nav_b1   = (const float*)d_in[19];
    const float* nav_W2   = (const float*)d_in[20];
    const float* nav_b2   = (const float*)d_in[21];
    float* out = (float*)d_out;

    // ---- workspace carve-up (256B aligned regions) ----
    char* w = (char*)d_ws;
    size_t off = 0;
    auto alloc = [&](size_t bytes) -> char* {
        char* p = w + off;
        off = (off + bytes + 255) & ~(size_t)255;
        return p;
    };
    float* hA      = (float*)alloc((size_t)NN * HID * 4);
    float* xh      = (float*)alloc((size_t)NN * HID * 4);
    float* asrc    = (float*)alloc((size_t)NN * HEADS * 4);
    float* adst    = (float*)alloc((size_t)NN * HEADS * 4);
    float* alpha   = (float*)alloc((size_t)ETOT * HEADS * 4);
    int*   counts  = (int*)  alloc((size_t)NN * 4);
    int*   offsets = (int*)  alloc((size_t)NN * 4);
    int*   fill    = (int*)  alloc((size_t)NN * 4);
    int*   perm    = (int*)  alloc((size_t)ETOT * 4);
    float* w_e     = (float*)alloc((size_t)LAYERS * EDIM * HEADS * 4);
    float* was     = (float*)alloc((size_t)LAYERS * HID * HEADS * 4);
    float* wad     = (float*)alloc((size_t)LAYERS * HID * HEADS * 4);
    float* mean_s  = (float*)alloc(EDIM * 4);
    float* mean_al = (float*)alloc(LAYERS * HEADS * 4);
    float* gsum    = (float*)alloc((size_t)BGR * HID * 4);
    float* gcnt    = (float*)alloc(BGR * 4);

    float* hOut = out;   // d_out h-region doubles as ping-pong buffer

    // ---- zero the accumulators ----
    hipMemsetAsync(mean_s, 0, EDIM * 4, stream);
    hipMemsetAsync(counts, 0, (size_t)NN * 4, stream);
    hipMemsetAsync(fill,   0, (size_t)NN * 4, stream);
    hipMemsetAsync(gsum,   0, (size_t)BGR * HID * 4, stream);
    hipMemsetAsync(gcnt,   0, BGR * 4, stream);

    // ---- one-time prep ----
    mean_ea_kernel<<<256, 256, 0, stream>>>(ea, mean_s);
    precompute_kernel<<<LAYERS, HID, 0, stream>>>(lin_W, lin_eW, att_src, att_dst,
                                                  att_edge, mean_s, was, wad, w_e, mean_al);
    proj_kernel<<<NN, HID, 0, stream>>>(x, proj_W, proj_b, hA);

    int eblocks = (ETOT + 255) / 256;
    hist_kernel<<<eblocks, 256, 0, stream>>>(ei, counts);
    scan_kernel<<<1, 1024, 0, stream>>>(counts, offsets);
    scatter_kernel<<<eblocks, 256, 0, stream>>>(ei, offsets, fill, perm);

    // ---- 3 GAT layers, ping-pong hA <-> hOut(d_out) ----
    const float* hin = hA;
    float* hout = hOut;
    for (int l = 0; l < LAYERS; l++) {
        xh_kernel<<<NN, HID, 0, stream>>>(hin, lin_W + (size_t)l * HID * HID,
                                          was + (size_t)l * HID * HEADS,
                                          wad + (size_t)l * HID * HEADS,
                                          xh, asrc, adst);
        edge_alpha_kernel<<<eblocks, 256, 0, stream>>>(ei, ea, asrc, adst,
                                                       w_e + (size_t)l * EDIM * HEADS,
                                                       mean_al + (size_t)l * HEADS, alpha);
        aggregate_kernel<<<(NN + 3) / 4, 256, 0, stream>>>(ei, perm, offsets, counts,
                                                           alpha, xh, hin,
                                                           conv_bias + (size_t)l * HID,
                                                           ln_g + (size_t)l * HID,
                                                           ln_b + (size_t)l * HID, hout);
        // swap
        const float* tmp = hin;
        hin = hout;
        hout = (float*)tmp;
    }
    // after 3 swaps: final h is in hOut(d_out) region; hin points at it now.

    // ---- pooling + heads ----
    pool_kernel<<<(NN + 3) / 4, 256, 0, stream>>>(out, batch, gsum, gcnt);
    head_kernel<<<BGR, HID, 0, stream>>>(gsum, gcnt, sc_W1, sc_b1, sc_W2, sc_b2,
                                         nav_W1, nav_b1, nav_W2, nav_b2, out);
}

// Round 3
// 988.003 us; speedup vs baseline: 1.9959x; 1.9959x over previous
//
#include <hip/hip_runtime.h>
#include <hip/hip_bf16.h>

// Problem constants (from reference)
constexpr int NN   = 50000;    // nodes
constexpr int NE   = 800000;   // edges (without self loops)
constexpr int ETOT = NE + NN;  // edges + self loops
constexpr int BGR  = 64;       // graphs
constexpr int HID  = 128;
constexpr int HEADS= 4;
constexpr int CDIM = 32;
constexpr int EDIM = 16;
constexpr int NDIM = 8;
constexpr int LAYERS = 3;
constexpr int HALF = 64;       // HID/2
constexpr int NCLS = 6;
constexpr int NAVD = 4;

// d_out layout (flat f32): h[NN*HID], scene[BGR*NCLS], nav[BGR*NAVD], graph[BGR*HID]
constexpr int OUT_SCENE = NN * HID;
constexpr int OUT_NAV   = OUT_SCENE + BGR*NCLS;
constexpr int OUT_GRAPH = OUT_NAV + BGR*NAVD;

// ---------------- mean of edge_attr (sums; divided later) ----------------
__global__ void mean_ea_kernel(const float* __restrict__ ea, float* __restrict__ mean_sum) {
    __shared__ float sdata[256];
    int tid = threadIdx.x;
    float acc = 0.f;
    int stride = gridDim.x * blockDim.x;            // multiple of 16
    for (int i = blockIdx.x * blockDim.x + tid; i < NE * EDIM; i += stride)
        acc += ea[i];
    sdata[tid] = acc;
    __syncthreads();
    for (int off = 128; off >= 16; off >>= 1) {
        if (tid < off) sdata[tid] += sdata[tid + off];
        __syncthreads();
    }
    if (tid < 16) atomicAdd(&mean_sum[tid], sdata[tid]);
}

// ---------------- per-layer folded edge-attention matrix ----------------
// w_e[l][k][h] = sum_c We_l[k, h*C+c] * att_edge[l,h,c]
// mean_alpha[l][h] = mean_ea . w_e[l][:,h]
__global__ void precompute_kernel(const float* __restrict__ lin_edge_W,
                                  const float* __restrict__ att_edge,
                                  const float* __restrict__ mean_sum,
                                  float* __restrict__ w_e, float* __restrict__ mean_alpha) {
    int l = blockIdx.x;
    int t = threadIdx.x;   // 64 threads
    __shared__ float we_s[EDIM * HEADS];
    const float* We = lin_edge_W + l * EDIM * HID;
    const float* ae = att_edge   + l * HEADS * CDIM;
    if (t < EDIM) {
        #pragma unroll
        for (int h = 0; h < HEADS; h++) {
            float s = 0.f;
            #pragma unroll
            for (int c = 0; c < CDIM; c++)
                s += We[t * HID + h * CDIM + c] * ae[h * CDIM + c];
            we_s[t * HEADS + h] = s;
            w_e[(l * EDIM + t) * HEADS + h] = s;
        }
    }
    __syncthreads();
    if (t < HEADS) {
        float s = 0.f;
        #pragma unroll
        for (int k = 0; k < EDIM; k++)
            s += (mean_sum[k] * (1.f / (float)NE)) * we_s[k * HEADS + t];
        mean_alpha[l * HEADS + t] = s;
    }
}

// ---------------- initial projection: h = relu(x @ proj_W + proj_b) ----------------
__global__ void proj_kernel(const float* __restrict__ x, const float* __restrict__ pW,
                            const float* __restrict__ pb, float* __restrict__ h) {
    int node = blockIdx.x;
    int t = threadIdx.x;   // 128
    __shared__ float xr[NDIM];
    if (t < NDIM) xr[t] = x[node * NDIM + t];
    __syncthreads();
    float acc = pb[t];
    #pragma unroll
    for (int k = 0; k < NDIM; k++) acc += xr[k] * pW[k * HID + t];
    h[node * HID + t] = fmaxf(acc, 0.f);
}

// ---------------- xh = h @ W ; a_src/a_dst from xh via shfl reduce ----------------
__global__ void xh_kernel(const float* __restrict__ hin, const float* __restrict__ W,
                          const float* __restrict__ As, const float* __restrict__ Ad,
                          float* __restrict__ xh, float* __restrict__ asrc,
                          float* __restrict__ adst) {
    int node = blockIdx.x;
    int t = threadIdx.x;   // 128
    __shared__ float hr[HID];
    hr[t] = hin[node * HID + t];
    __syncthreads();
    float acc = 0.f;
    #pragma unroll 8
    for (int k = 0; k < HID; k++) acc += hr[k] * W[k * HID + t];
    xh[node * HID + t] = acc;
    // a_src[n,h] = sum_c xh[n,h,c]*att_src[h,c] ; head = t>>5, c = t&31
    float rs = acc * As[t];
    float rd = acc * Ad[t];
    #pragma unroll
    for (int off = 16; off > 0; off >>= 1) {
        rs += __shfl_xor(rs, off);
        rd += __shfl_xor(rd, off);
    }
    if ((t & 31) == 0) {
        int hidx = t >> 5;
        asrc[node * HEADS + hidx] = rs;
        adst[node * HEADS + hidx] = rd;
    }
}

// ---------------- CSR build ----------------
__global__ void hist_kernel(const int* __restrict__ ei, int* __restrict__ counts) {
    int e = blockIdx.x * blockDim.x + threadIdx.x;
    if (e >= ETOT) return;
    int d = (e < NE) ? ei[NE + e] : (e - NE);
    atomicAdd(&counts[d], 1);
}

// single-block shfl-based exclusive scan of counts -> offsets
__global__ void scan_kernel(const int* __restrict__ counts, int* __restrict__ offsets) {
    __shared__ int wsum[16];
    __shared__ int carry_s;
    int lane = threadIdx.x & 63;
    int wid  = threadIdx.x >> 6;
    if (threadIdx.x == 0) carry_s = 0;
    __syncthreads();
    for (int base = 0; base < NN; base += 1024) {
        int i = base + threadIdx.x;
        int v = (i < NN) ? counts[i] : 0;
        int x = v;
        #pragma unroll
        for (int off = 1; off < 64; off <<= 1) {
            int y = __shfl_up(x, off);
            if (lane >= off) x += y;
        }
        if (lane == 63) wsum[wid] = x;
        __syncthreads();
        if (wid == 0) {
            int w = (lane < 16) ? wsum[lane] : 0;
            #pragma unroll
            for (int off = 1; off < 16; off <<= 1) {
                int y = __shfl_up(w, off);
                if (lane >= off) w += y;
            }
            if (lane < 16) wsum[lane] = w;   // inclusive scan of wave sums
        }
        __syncthreads();
        int waveoff = (wid == 0) ? 0 : wsum[wid - 1];
        int carry = carry_s;
        if (i < NN) offsets[i] = carry + waveoff + x - v;   // exclusive
        __syncthreads();
        if (threadIdx.x == 0) carry_s = carry + wsum[15];
        __syncthreads();
    }
}

// scatter: record inverse permutation epos[e] and CSR-ordered source node ids
__global__ void scatter_kernel(const int* __restrict__ ei, const int* __restrict__ offsets,
                               int* __restrict__ fill, int* __restrict__ epos,
                               int* __restrict__ src_p) {
    int e = blockIdx.x * blockDim.x + threadIdx.x;
    if (e >= ETOT) return;
    int s, d;
    if (e < NE) { s = ei[e]; d = ei[NE + e]; }
    else        { s = d = e - NE; }
    int pos = offsets[d] + atomicAdd(&fill[d], 1);
    epos[e]   = pos;
    src_p[pos] = s;
}

// ---------------- per-edge attention logits, written in CSR order ----------------
__global__ void edge_alpha_kernel(const int* __restrict__ ei, const float* __restrict__ ea,
                                  const float* __restrict__ asrc, const float* __restrict__ adst,
                                  const float* __restrict__ w_e, const float* __restrict__ mean_alpha,
                                  const int* __restrict__ epos, float* __restrict__ alpha_p) {
    __shared__ float we_s[EDIM * HEADS];
    if (threadIdx.x < EDIM * HEADS) we_s[threadIdx.x] = w_e[threadIdx.x];
    __syncthreads();
    int e = blockIdx.x * blockDim.x + threadIdx.x;
    if (e >= ETOT) return;
    int s, d;
    float e0, e1, e2, e3;
    if (e < NE) {
        s = ei[e];
        d = ei[NE + e];
        const float* er = ea + (size_t)e * EDIM;
        e0 = e1 = e2 = e3 = 0.f;
        #pragma unroll
        for (int k = 0; k < EDIM; k++) {
            float xv = er[k];
            e0 += xv * we_s[k * HEADS + 0];
            e1 += xv * we_s[k * HEADS + 1];
            e2 += xv * we_s[k * HEADS + 2];
            e3 += xv * we_s[k * HEADS + 3];
        }
    } else {
        s = d = e - NE;
        float4 ma = *(const float4*)mean_alpha;
        e0 = ma.x; e1 = ma.y; e2 = ma.z; e3 = ma.w;
    }
    float4 A = *(const float4*)(asrc + s * HEADS);
    float4 D = *(const float4*)(adst + d * HEADS);
    float a0 = A.x + D.x + e0, a1 = A.y + D.y + e1;
    float a2 = A.z + D.z + e2, a3 = A.w + D.w + e3;
    a0 = (a0 > 0.f) ? a0 : 0.2f * a0;
    a1 = (a1 > 0.f) ? a1 : 0.2f * a1;
    a2 = (a2 > 0.f) ? a2 : 0.2f * a2;
    a3 = (a3 > 0.f) ? a3 : 0.2f * a3;
    *(float4*)(alpha_p + (size_t)epos[e] * HEADS) = make_float4(a0, a1, a2, a3);
}

// ---------------- per-node aggregation (online softmax) + bias + residual + LN + relu
// One 64-lane wave per node; lane owns channels 2*lane, 2*lane+1; head = lane>>4.
__launch_bounds__(256)
__global__ void aggregate_kernel(const int* __restrict__ src_p, const int* __restrict__ offsets,
                                 const int* __restrict__ counts,
                                 const float* __restrict__ alpha_p, const float* __restrict__ xh,
                                 const float* __restrict__ hres, const float* __restrict__ bias,
                                 const float* __restrict__ lng, const float* __restrict__ lnb,
                                 float* __restrict__ hout) {
    int wid  = threadIdx.x >> 6;
    int lane = threadIdx.x & 63;
    int node = blockIdx.x * 4 + wid;
    if (node >= NN) return;
    int start = offsets[node];
    int deg   = counts[node];
    int head  = lane >> 4;
    int c0    = lane * 2;

    float m = -1e30f, dsum = 0.f, acc0 = 0.f, acc1 = 0.f;
    int j = 0;
    for (; j + 1 < deg; j += 2) {
        int p0i = start + j, p1i = start + j + 1;
        int s0 = src_p[p0i];
        int s1 = src_p[p1i];
        float a0 = alpha_p[(size_t)p0i * HEADS + head];
        float a1 = alpha_p[(size_t)p1i * HEADS + head];
        float2 v0 = *(const float2*)(xh + (size_t)s0 * HID + c0);
        float2 v1 = *(const float2*)(xh + (size_t)s1 * HID + c0);
        float mn = fmaxf(m, fmaxf(a0, a1));
        float sc = __expf(m - mn);
        float q0 = __expf(a0 - mn);
        float q1 = __expf(a1 - mn);
        dsum = dsum * sc + q0 + q1;
        acc0 = acc0 * sc + q0 * v0.x + q1 * v1.x;
        acc1 = acc1 * sc + q0 * v0.y + q1 * v1.y;
        m = mn;
    }
    if (j < deg) {
        int pi = start + j;
        int s0 = src_p[pi];
        float a0 = alpha_p[(size_t)pi * HEADS + head];
        float2 v0 = *(const float2*)(xh + (size_t)s0 * HID + c0);
        float mn = fmaxf(m, a0);
        float sc = __expf(m - mn);
        float q0 = __expf(a0 - mn);
        dsum = dsum * sc + q0;
        acc0 = acc0 * sc + q0 * v0.x;
        acc1 = acc1 * sc + q0 * v0.y;
    }
    float inv = 1.f / (dsum + 1e-16f);
    float2 r = *(const float2*)(hres + (size_t)node * HID + c0);
    float v0 = acc0 * inv + bias[c0]     + r.x;
    float v1 = acc1 * inv + bias[c0 + 1] + r.y;

    // LayerNorm over 128 channels spread 2-per-lane across the wave
    float ssum = v0 + v1;
    #pragma unroll
    for (int off = 32; off > 0; off >>= 1) ssum += __shfl_xor(ssum, off);
    float mu = ssum * (1.f / 128.f);
    float d0 = v0 - mu, d1 = v1 - mu;
    float vs = d0 * d0 + d1 * d1;
    #pragma unroll
    for (int off = 32; off > 0; off >>= 1) vs += __shfl_xor(vs, off);
    float rstd = rsqrtf(vs * (1.f / 128.f) + 1e-5f);
    float y0 = fmaxf(d0 * rstd * lng[c0]     + lnb[c0],     0.f);
    float y1 = fmaxf(d1 * rstd * lng[c0 + 1] + lnb[c0 + 1], 0.f);
    *(float2*)(hout + (size_t)node * HID + c0) = make_float2(y0, y1);
}

// ---------------- fused pool (sorted batch -> contiguous ranges) + heads ----------------
__launch_bounds__(512)
__global__ void head_kernel(const float* __restrict__ h, const int* __restrict__ batch,
                            const float* __restrict__ scW1, const float* __restrict__ scb1,
                            const float* __restrict__ scW2, const float* __restrict__ scb2,
                            const float* __restrict__ nvW1, const float* __restrict__ nvb1,
                            const float* __restrict__ nvW2, const float* __restrict__ nvb2,
                            float* __restrict__ out) {
    int b = blockIdx.x;
    int t = threadIdx.x;   // 512
    __shared__ float part[4][HID];
    __shared__ float gr[HID];
    __shared__ float h1[HALF];
    __shared__ float h2[HALF];
    // lower_bound(batch, b) / lower_bound(batch, b+1) on sorted batch
    int lo = 0, hi = NN;
    while (lo < hi) { int mid = (lo + hi) >> 1; if (batch[mid] < b) lo = mid + 1; else hi = mid; }
    int s0 = lo;
    lo = s0; hi = NN;
    while (lo < hi) { int mid = (lo + hi) >> 1; if (batch[mid] < b + 1) lo = mid + 1; else hi = mid; }
    int e0 = lo;
    int cnt = e0 - s0;

    int r  = t >> 7;      // 0..3
    int ch = t & 127;
    float acc = 0.f;
    for (int i = s0 + r; i < e0; i += 4) acc += h[(size_t)i * HID + ch];
    part[r][ch] = acc;
    __syncthreads();
    if (t < HID) {
        float g = (part[0][t] + part[1][t] + part[2][t] + part[3][t]) / fmaxf((float)cnt, 1.f);
        gr[t] = g;
        out[OUT_GRAPH + b * HID + t] = g;
    }
    __syncthreads();
    if (t < HALF) {
        float a = scb1[t], n = nvb1[t];
        #pragma unroll 4
        for (int k = 0; k < HID; k++) {
            float g = gr[k];
            a += g * scW1[k * HALF + t];
            n += g * nvW1[k * HALF + t];
        }
        h1[t] = fmaxf(a, 0.f);
        h2[t] = fmaxf(n, 0.f);
    }
    __syncthreads();
    if (t < NCLS) {
        float a = scb2[t];
        #pragma unroll 8
        for (int j = 0; j < HALF; j++) a += h1[j] * scW2[j * NCLS + t];
        out[OUT_SCENE + b * NCLS + t] = a;
    }
    if (t >= 64 && t < 64 + NAVD) {
        int q = t - 64;
        float a = nvb2[q];
        #pragma unroll 8
        for (int j = 0; j < HALF; j++) a += h2[j] * nvW2[j * NAVD + q];
        out[OUT_NAV + b * NAVD + q] = 1.f / (1.f + expf(-a));
    }
}

extern "C" void kernel_launch(void* const* d_in, const int* in_sizes, int n_in,
                              void* d_out, int out_size, void* d_ws, size_t ws_size,
                              hipStream_t stream) {
    const float* x        = (const float*)d_in[0];
    const int*   ei       = (const int*)  d_in[1];
    const float* ea       = (const float*)d_in[2];
    const int*   batch    = (const int*)  d_in[3];
    const float* proj_W   = (const float*)d_in[4];
    const float* proj_b   = (const float*)d_in[5];
    const float* lin_W    = (const float*)d_in[6];
    const float* lin_eW   = (const float*)d_in[7];
    const float* att_src  = (const float*)d_in[8];
    const float* att_dst  = (const float*)d_in[9];
    const float* att_edge = (const float*)d_in[10];
    const float* conv_bias= (const float*)d_in[11];
    const float* ln_g     = (const float*)d_in[12];
    const float* ln_b     = (const float*)d_in[13];
    const float* sc_W1    = (const float*)d_in[14];
    const float* sc_b1    = (const float*)d_in[15];
    const float* sc_W2    = (const float*)d_in[16];
    const float* sc_b2    = (const float*)d_in[17];
    const float* nav_W1   = (const float*)d_in[18];
    const float* nav_b1   = (const float*)d_in[19];
    const float* nav_W2   = (const float*)d_in[20];
    const float* nav_b2   = (const float*)d_in[21];
    float* out = (float*)d_out;

    // ---- workspace carve-up (256B aligned regions) ----
    char* w = (char*)d_ws;
    size_t off = 0;
    auto alloc = [&](size_t bytes) -> char* {
        char* p = w + off;
        off = (off + bytes + 255) & ~(size_t)255;
        return p;
    };
    float* hA      = (float*)alloc((size_t)NN * HID * 4);
    float* xh      = (float*)alloc((size_t)NN * HID * 4);
    float* asrc    = (float*)alloc((size_t)NN * HEADS * 4);
    float* adst    = (float*)alloc((size_t)NN * HEADS * 4);
    float* alpha_p = (float*)alloc((size_t)ETOT * HEADS * 4);
    int*   counts  = (int*)  alloc((size_t)NN * 4);
    int*   offsets = (int*)  alloc((size_t)NN * 4);
    int*   fill    = (int*)  alloc((size_t)NN * 4);
    int*   epos    = (int*)  alloc((size_t)ETOT * 4);
    int*   src_p   = (int*)  alloc((size_t)ETOT * 4);
    float* w_e     = (float*)alloc((size_t)LAYERS * EDIM * HEADS * 4);
    float* mean_s  = (float*)alloc(EDIM * 4);
    float* mean_al = (float*)alloc(LAYERS * HEADS * 4);

    // ---- zero the accumulators ----
    hipMemsetAsync(mean_s, 0, EDIM * 4, stream);
    hipMemsetAsync(counts, 0, (size_t)NN * 4, stream);
    hipMemsetAsync(fill,   0, (size_t)NN * 4, stream);

    // ---- one-time prep ----
    mean_ea_kernel<<<256, 256, 0, stream>>>(ea, mean_s);
    precompute_kernel<<<LAYERS, 64, 0, stream>>>(lin_eW, att_edge, mean_s, w_e, mean_al);
    proj_kernel<<<NN, HID, 0, stream>>>(x, proj_W, proj_b, hA);

    int eblocks = (ETOT + 255) / 256;
    hist_kernel<<<eblocks, 256, 0, stream>>>(ei, counts);
    scan_kernel<<<1, 1024, 0, stream>>>(counts, offsets);
    scatter_kernel<<<eblocks, 256, 0, stream>>>(ei, offsets, fill, epos, src_p);

    // ---- 3 GAT layers, ping-pong hA <-> d_out h-region ----
    const float* hin = hA;
    float* hout = out;
    for (int l = 0; l < LAYERS; l++) {
        xh_kernel<<<NN, HID, 0, stream>>>(hin, lin_W + (size_t)l * HID * HID,
                                          att_src + (size_t)l * HID,
                                          att_dst + (size_t)l * HID,
                                          xh, asrc, adst);
        edge_alpha_kernel<<<eblocks, 256, 0, stream>>>(ei, ea, asrc, adst,
                                                       w_e + (size_t)l * EDIM * HEADS,
                                                       mean_al + (size_t)l * HEADS,
                                                       epos, alpha_p);
        aggregate_kernel<<<(NN + 3) / 4, 256, 0, stream>>>(src_p, offsets, counts,
                                                           alpha_p, xh, hin,
                                                           conv_bias + (size_t)l * HID,
                                                           ln_g + (size_t)l * HID,
                                                           ln_b + (size_t)l * HID, hout);
        const float* tmp = hin;
        hin = hout;
        hout = (float*)tmp;
    }
    // final h is in the d_out h-region

    // ---- fused pool + heads ----
    head_kernel<<<BGR, 512, 0, stream>>>(out, batch, sc_W1, sc_b1, sc_W2, sc_b2,
                                         nav_W1, nav_b1, nav_W2, nav_b2, out);
}

// Round 4
// 891.202 us; speedup vs baseline: 2.2127x; 1.1086x over previous
//
#include <hip/hip_runtime.h>
#include <hip/hip_bf16.h>

// Problem constants (from reference)
constexpr int NN   = 50000;    // nodes
constexpr int NE   = 800000;   // edges (without self loops)
constexpr int ETOT = NE + NN;  // edges + self loops
constexpr int BGR  = 64;       // graphs
constexpr int HID  = 128;
constexpr int HEADS= 4;
constexpr int CDIM = 32;
constexpr int EDIM = 16;
constexpr int NDIM = 8;
constexpr int LAYERS = 3;
constexpr int HALF = 64;       // HID/2
constexpr int NCLS = 6;
constexpr int NAVD = 4;

// d_out layout (flat f32): h[NN*HID], scene[BGR*NCLS], nav[BGR*NAVD], graph[BGR*HID]
constexpr int OUT_SCENE = NN * HID;
constexpr int OUT_NAV   = OUT_SCENE + BGR*NCLS;
constexpr int OUT_GRAPH = OUT_NAV + BGR*NAVD;

// ---------------- mean of edge_attr (sums; divided later) ----------------
__global__ void mean_ea_kernel(const float* __restrict__ ea, float* __restrict__ mean_sum) {
    __shared__ float sdata[256];
    int tid = threadIdx.x;
    float acc = 0.f;
    int stride = gridDim.x * blockDim.x;            // multiple of 16
    for (int i = blockIdx.x * blockDim.x + tid; i < NE * EDIM; i += stride)
        acc += ea[i];
    sdata[tid] = acc;
    __syncthreads();
    for (int off = 128; off >= 16; off >>= 1) {
        if (tid < off) sdata[tid] += sdata[tid + off];
        __syncthreads();
    }
    if (tid < 16) atomicAdd(&mean_sum[tid], sdata[tid]);
}

// ---------------- per-layer folded edge-attention matrix ----------------
__global__ void precompute_kernel(const float* __restrict__ lin_edge_W,
                                  const float* __restrict__ att_edge,
                                  const float* __restrict__ mean_sum,
                                  float* __restrict__ w_e, float* __restrict__ mean_alpha) {
    int l = blockIdx.x;
    int t = threadIdx.x;   // 64 threads
    __shared__ float we_s[EDIM * HEADS];
    const float* We = lin_edge_W + l * EDIM * HID;
    const float* ae = att_edge   + l * HEADS * CDIM;
    if (t < EDIM) {
        #pragma unroll
        for (int h = 0; h < HEADS; h++) {
            float s = 0.f;
            #pragma unroll
            for (int c = 0; c < CDIM; c++)
                s += We[t * HID + h * CDIM + c] * ae[h * CDIM + c];
            we_s[t * HEADS + h] = s;
            w_e[(l * EDIM + t) * HEADS + h] = s;
        }
    }
    __syncthreads();
    if (t < HEADS) {
        float s = 0.f;
        #pragma unroll
        for (int k = 0; k < EDIM; k++)
            s += (mean_sum[k] * (1.f / (float)NE)) * we_s[k * HEADS + t];
        mean_alpha[l * HEADS + t] = s;
    }
}

// ---------------- initial projection: h = relu(x @ proj_W + proj_b) ----------------
__global__ void proj_kernel(const float* __restrict__ x, const float* __restrict__ pW,
                            const float* __restrict__ pb, float* __restrict__ h) {
    int node = blockIdx.x;
    int t = threadIdx.x;   // 128
    __shared__ float xr[NDIM];
    if (t < NDIM) xr[t] = x[node * NDIM + t];
    __syncthreads();
    float acc = pb[t];
    #pragma unroll
    for (int k = 0; k < NDIM; k++) acc += xr[k] * pW[k * HID + t];
    h[node * HID + t] = fmaxf(acc, 0.f);
}

// ---------------- xh = h @ W (W staged in LDS, 4 nodes / block-iter) ----------------
// Block 256 = 4 waves. which = wave-pair id (0,1). Wave covers 64 channels of 2 nodes.
__launch_bounds__(256, 2)
__global__ void xh_kernel(const float* __restrict__ hin, const float* __restrict__ W,
                          const float* __restrict__ As, const float* __restrict__ Ad,
                          float* __restrict__ xh, float* __restrict__ asrc,
                          float* __restrict__ adst) {
    __shared__ float Ws[HID * HID];          // 64 KB: Ws[k*128 + c]
    {
        const float4* Wv = (const float4*)W;
        float4* Wsv = (float4*)Ws;
        #pragma unroll
        for (int i = 0; i < (HID * HID / 4) / 256; i++)
            Wsv[i * 256 + threadIdx.x] = Wv[i * 256 + threadIdx.x];
    }
    __syncthreads();
    int t = threadIdx.x;
    int c = t & 127;
    int lane = t & 63;
    int which = __builtin_amdgcn_readfirstlane(t >> 7);   // wave-uniform 0/1
    float myAs = As[c], myAd = Ad[c];
    int head = c >> 5;

    for (int base = blockIdx.x * 4; base < NN; base += gridDim.x * 4) {
        int n0 = base + which * 2;
        int n1 = n0 + 1;
        const float* __restrict__ h0 = hin + (size_t)n0 * HID;
        const float* __restrict__ h1 = hin + (size_t)n1 * HID;
        float a0e = 0.f, a0o = 0.f, a1e = 0.f, a1o = 0.f;
        #pragma unroll 8
        for (int k = 0; k < HID; k += 2) {
            float w0 = Ws[k * HID + c];
            float w1 = Ws[(k + 1) * HID + c];
            float h0e = h0[k], h0o = h0[k + 1];
            float h1e = h1[k], h1o = h1[k + 1];
            a0e = fmaf(h0e, w0, a0e);
            a0o = fmaf(h0o, w1, a0o);
            a1e = fmaf(h1e, w0, a1e);
            a1o = fmaf(h1o, w1, a1o);
        }
        float acc0 = a0e + a0o;
        float acc1 = a1e + a1o;
        xh[(size_t)n0 * HID + c] = acc0;
        xh[(size_t)n1 * HID + c] = acc1;
        // attention dots: reduce within 32-lane (per-head) groups
        float rs0 = acc0 * myAs, rd0 = acc0 * myAd;
        float rs1 = acc1 * myAs, rd1 = acc1 * myAd;
        #pragma unroll
        for (int off = 16; off > 0; off >>= 1) {
            rs0 += __shfl_xor(rs0, off);
            rd0 += __shfl_xor(rd0, off);
            rs1 += __shfl_xor(rs1, off);
            rd1 += __shfl_xor(rd1, off);
        }
        if ((lane & 31) == 0) {
            asrc[n0 * HEADS + head] = rs0;
            adst[n0 * HEADS + head] = rd0;
            asrc[n1 * HEADS + head] = rs1;
            adst[n1 * HEADS + head] = rd1;
        }
    }
}

// ---------------- CSR build ----------------
__global__ void hist_kernel(const int* __restrict__ ei, int* __restrict__ counts) {
    int e = blockIdx.x * blockDim.x + threadIdx.x;
    if (e >= ETOT) return;
    int d = (e < NE) ? ei[NE + e] : (e - NE);
    atomicAdd(&counts[d], 1);
}

// single-block shfl-based exclusive scan of counts -> offsets
__global__ void scan_kernel(const int* __restrict__ counts, int* __restrict__ offsets) {
    __shared__ int wsum[16];
    __shared__ int carry_s;
    int lane = threadIdx.x & 63;
    int wid  = threadIdx.x >> 6;
    if (threadIdx.x == 0) carry_s = 0;
    __syncthreads();
    for (int base = 0; base < NN; base += 1024) {
        int i = base + threadIdx.x;
        int v = (i < NN) ? counts[i] : 0;
        int x = v;
        #pragma unroll
        for (int off = 1; off < 64; off <<= 1) {
            int y = __shfl_up(x, off);
            if (lane >= off) x += y;
        }
        if (lane == 63) wsum[wid] = x;
        __syncthreads();
        if (wid == 0) {
            int w = (lane < 16) ? wsum[lane] : 0;
            #pragma unroll
            for (int off = 1; off < 16; off <<= 1) {
                int y = __shfl_up(w, off);
                if (lane >= off) w += y;
            }
            if (lane < 16) wsum[lane] = w;   // inclusive scan of wave sums
        }
        __syncthreads();
        int waveoff = (wid == 0) ? 0 : wsum[wid - 1];
        int carry = carry_s;
        if (i < NN) offsets[i] = carry + waveoff + x - v;   // exclusive
        __syncthreads();
        if (threadIdx.x == 0) carry_s = carry + wsum[15];
        __syncthreads();
    }
}

// scatter: record inverse permutation epos[e] and CSR-ordered source node ids
__global__ void scatter_kernel(const int* __restrict__ ei, const int* __restrict__ offsets,
                               int* __restrict__ fill, int* __restrict__ epos,
                               int* __restrict__ src_p) {
    int e = blockIdx.x * blockDim.x + threadIdx.x;
    if (e >= ETOT) return;
    int s, d;
    if (e < NE) { s = ei[e]; d = ei[NE + e]; }
    else        { s = d = e - NE; }
    int pos = offsets[d] + atomicAdd(&fill[d], 1);
    epos[e]   = pos;
    src_p[pos] = s;
}

// ---------------- raw edge attention terms (ea @ w_e), CSR order, nl layers ----------------
__global__ void eterm_kernel(const float* __restrict__ ea,
                             const float* __restrict__ w_e, const float* __restrict__ mean_alpha,
                             const int* __restrict__ epos, float* __restrict__ dst, int nl) {
    __shared__ float we_s[LAYERS * EDIM * HEADS];
    __shared__ float ma_s[LAYERS * HEADS];
    if (threadIdx.x < nl * EDIM * HEADS) we_s[threadIdx.x] = w_e[threadIdx.x];
    if (threadIdx.x < nl * HEADS) ma_s[threadIdx.x] = mean_alpha[threadIdx.x];
    __syncthreads();
    int e = blockIdx.x * blockDim.x + threadIdx.x;
    if (e >= ETOT) return;
    int pos = epos[e];
    if (e < NE) {
        float er[EDIM];
        const float4* ev = (const float4*)(ea + (size_t)e * EDIM);
        float4 v0 = ev[0], v1 = ev[1], v2 = ev[2], v3 = ev[3];
        er[0]=v0.x; er[1]=v0.y; er[2]=v0.z; er[3]=v0.w;
        er[4]=v1.x; er[5]=v1.y; er[6]=v1.z; er[7]=v1.w;
        er[8]=v2.x; er[9]=v2.y; er[10]=v2.z; er[11]=v2.w;
        er[12]=v3.x; er[13]=v3.y; er[14]=v3.z; er[15]=v3.w;
        for (int l = 0; l < nl; l++) {
            float e0 = 0.f, e1 = 0.f, e2 = 0.f, e3 = 0.f;
            const float* ws = we_s + l * EDIM * HEADS;
            #pragma unroll
            for (int k = 0; k < EDIM; k++) {
                float xv = er[k];
                e0 += xv * ws[k * HEADS + 0];
                e1 += xv * ws[k * HEADS + 1];
                e2 += xv * ws[k * HEADS + 2];
                e3 += xv * ws[k * HEADS + 3];
            }
            *(float4*)(dst + (size_t)l * ETOT * HEADS + (size_t)pos * HEADS)
                = make_float4(e0, e1, e2, e3);
        }
    } else {
        for (int l = 0; l < nl; l++) {
            *(float4*)(dst + (size_t)l * ETOT * HEADS + (size_t)pos * HEADS)
                = make_float4(ma_s[l*HEADS+0], ma_s[l*HEADS+1], ma_s[l*HEADS+2], ma_s[l*HEADS+3]);
        }
    }
}

// ---------------- per-node aggregation (inline alpha + online softmax) + LN ----------------
// One 64-lane wave per node; lane owns channels 2*lane, 2*lane+1; head = lane>>4.
__launch_bounds__(256)
__global__ void aggregate_kernel(const int* __restrict__ src_p, const int* __restrict__ offsets,
                                 const int* __restrict__ counts,
                                 const float* __restrict__ eterm,
                                 const float* __restrict__ asrc, const float* __restrict__ adst,
                                 const float* __restrict__ xh,
                                 const float* __restrict__ hres, const float* __restrict__ bias,
                                 const float* __restrict__ lng, const float* __restrict__ lnb,
                                 float* __restrict__ hout) {
    int wid  = threadIdx.x >> 6;
    int lane = threadIdx.x & 63;
    int node = blockIdx.x * 4 + wid;
    if (node >= NN) return;
    int start = offsets[node];
    int deg   = counts[node];
    int head  = lane >> 4;
    int c0    = lane * 2;
    float ad_h = adst[node * HEADS + head];

    float m = -1e30f, dsum = 0.f, acc0 = 0.f, acc1 = 0.f;
    int j = 0;
    for (; j + 3 < deg; j += 4) {
        int p0 = start + j, p1 = p0 + 1, p2 = p0 + 2, p3 = p0 + 3;
        int s0 = src_p[p0], s1 = src_p[p1], s2 = src_p[p2], s3 = src_p[p3];
        float a0 = asrc[s0 * HEADS + head] + ad_h + eterm[(size_t)p0 * HEADS + head];
        float a1 = asrc[s1 * HEADS + head] + ad_h + eterm[(size_t)p1 * HEADS + head];
        float a2 = asrc[s2 * HEADS + head] + ad_h + eterm[(size_t)p2 * HEADS + head];
        float a3 = asrc[s3 * HEADS + head] + ad_h + eterm[(size_t)p3 * HEADS + head];
        a0 = (a0 > 0.f) ? a0 : 0.2f * a0;
        a1 = (a1 > 0.f) ? a1 : 0.2f * a1;
        a2 = (a2 > 0.f) ? a2 : 0.2f * a2;
        a3 = (a3 > 0.f) ? a3 : 0.2f * a3;
        float2 v0 = *(const float2*)(xh + (size_t)s0 * HID + c0);
        float2 v1 = *(const float2*)(xh + (size_t)s1 * HID + c0);
        float2 v2 = *(const float2*)(xh + (size_t)s2 * HID + c0);
        float2 v3 = *(const float2*)(xh + (size_t)s3 * HID + c0);
        float mn = fmaxf(m, fmaxf(fmaxf(a0, a1), fmaxf(a2, a3)));
        float sc = __expf(m - mn);
        float q0 = __expf(a0 - mn), q1 = __expf(a1 - mn);
        float q2 = __expf(a2 - mn), q3 = __expf(a3 - mn);
        dsum = fmaf(dsum, sc, (q0 + q1) + (q2 + q3));
        acc0 = fmaf(acc0, sc, fmaf(q0, v0.x, fmaf(q1, v1.x, fmaf(q2, v2.x, q3 * v3.x))));
        acc1 = fmaf(acc1, sc, fmaf(q0, v0.y, fmaf(q1, v1.y, fmaf(q2, v2.y, q3 * v3.y))));
        m = mn;
    }
    for (; j < deg; j++) {
        int pi = start + j;
        int s0 = src_p[pi];
        float a0 = asrc[s0 * HEADS + head] + ad_h + eterm[(size_t)pi * HEADS + head];
        a0 = (a0 > 0.f) ? a0 : 0.2f * a0;
        float2 v0 = *(const float2*)(xh + (size_t)s0 * HID + c0);
        float mn = fmaxf(m, a0);
        float sc = __expf(m - mn);
        float q0 = __expf(a0 - mn);
        dsum = fmaf(dsum, sc, q0);
        acc0 = fmaf(acc0, sc, q0 * v0.x);
        acc1 = fmaf(acc1, sc, q0 * v0.y);
        m = mn;
    }
    float inv = 1.f / (dsum + 1e-16f);
    float2 r = *(const float2*)(hres + (size_t)node * HID + c0);
    float v0 = acc0 * inv + bias[c0]     + r.x;
    float v1 = acc1 * inv + bias[c0 + 1] + r.y;

    // LayerNorm over 128 channels spread 2-per-lane across the wave
    float ssum = v0 + v1;
    #pragma unroll
    for (int off = 32; off > 0; off >>= 1) ssum += __shfl_xor(ssum, off);
    float mu = ssum * (1.f / 128.f);
    float d0 = v0 - mu, d1 = v1 - mu;
    float vs = d0 * d0 + d1 * d1;
    #pragma unroll
    for (int off = 32; off > 0; off >>= 1) vs += __shfl_xor(vs, off);
    float rstd = rsqrtf(vs * (1.f / 128.f) + 1e-5f);
    float y0 = fmaxf(d0 * rstd * lng[c0]     + lnb[c0],     0.f);
    float y1 = fmaxf(d1 * rstd * lng[c0 + 1] + lnb[c0 + 1], 0.f);
    *(float2*)(hout + (size_t)node * HID + c0) = make_float2(y0, y1);
}

// ---------------- fused pool (sorted batch -> contiguous ranges) + heads ----------------
__launch_bounds__(512)
__global__ void head_kernel(const float* __restrict__ h, const int* __restrict__ batch,
                            const float* __restrict__ scW1, const float* __restrict__ scb1,
                            const float* __restrict__ scW2, const float* __restrict__ scb2,
                            const float* __restrict__ nvW1, const float* __restrict__ nvb1,
                            const float* __restrict__ nvW2, const float* __restrict__ nvb2,
                            float* __restrict__ out) {
    int b = blockIdx.x;
    int t = threadIdx.x;   // 512
    __shared__ float part[4][HID];
    __shared__ float gr[HID];
    __shared__ float h1[HALF];
    __shared__ float h2[HALF];
    int lo = 0, hi = NN;
    while (lo < hi) { int mid = (lo + hi) >> 1; if (batch[mid] < b) lo = mid + 1; else hi = mid; }
    int s0 = lo;
    lo = s0; hi = NN;
    while (lo < hi) { int mid = (lo + hi) >> 1; if (batch[mid] < b + 1) lo = mid + 1; else hi = mid; }
    int e0 = lo;
    int cnt = e0 - s0;

    int r  = t >> 7;      // 0..3
    int ch = t & 127;
    float acc = 0.f;
    for (int i = s0 + r; i < e0; i += 4) acc += h[(size_t)i * HID + ch];
    part[r][ch] = acc;
    __syncthreads();
    if (t < HID) {
        float g = (part[0][t] + part[1][t] + part[2][t] + part[3][t]) / fmaxf((float)cnt, 1.f);
        gr[t] = g;
        out[OUT_GRAPH + b * HID + t] = g;
    }
    __syncthreads();
    if (t < HALF) {
        float a = scb1[t], n = nvb1[t];
        #pragma unroll 4
        for (int k = 0; k < HID; k++) {
            float g = gr[k];
            a += g * scW1[k * HALF + t];
            n += g * nvW1[k * HALF + t];
        }
        h1[t] = fmaxf(a, 0.f);
        h2[t] = fmaxf(n, 0.f);
    }
    __syncthreads();
    if (t < NCLS) {
        float a = scb2[t];
        #pragma unroll 8
        for (int j = 0; j < HALF; j++) a += h1[j] * scW2[j * NCLS + t];
        out[OUT_SCENE + b * NCLS + t] = a;
    }
    if (t >= 64 && t < 64 + NAVD) {
        int q = t - 64;
        float a = nvb2[q];
        #pragma unroll 8
        for (int j = 0; j < HALF; j++) a += h2[j] * nvW2[j * NAVD + q];
        out[OUT_NAV + b * NAVD + q] = 1.f / (1.f + expf(-a));
    }
}

extern "C" void kernel_launch(void* const* d_in, const int* in_sizes, int n_in,
                              void* d_out, int out_size, void* d_ws, size_t ws_size,
                              hipStream_t stream) {
    const float* x        = (const float*)d_in[0];
    const int*   ei       = (const int*)  d_in[1];
    const float* ea       = (const float*)d_in[2];
    const int*   batch    = (const int*)  d_in[3];
    const float* proj_W   = (const float*)d_in[4];
    const float* proj_b   = (const float*)d_in[5];
    const float* lin_W    = (const float*)d_in[6];
    const float* lin_eW   = (const float*)d_in[7];
    const float* att_src  = (const float*)d_in[8];
    const float* att_dst  = (const float*)d_in[9];
    const float* att_edge = (const float*)d_in[10];
    const float* conv_bias= (const float*)d_in[11];
    const float* ln_g     = (const float*)d_in[12];
    const float* ln_b     = (const float*)d_in[13];
    const float* sc_W1    = (const float*)d_in[14];
    const float* sc_b1    = (const float*)d_in[15];
    const float* sc_W2    = (const float*)d_in[16];
    const float* sc_b2    = (const float*)d_in[17];
    const float* nav_W1   = (const float*)d_in[18];
    const float* nav_b1   = (const float*)d_in[19];
    const float* nav_W2   = (const float*)d_in[20];
    const float* nav_b2   = (const float*)d_in[21];
    float* out = (float*)d_out;

    // ---- workspace carve-up (256B aligned regions) ----
    char* w = (char*)d_ws;
    size_t off = 0;
    auto alloc = [&](size_t bytes) -> char* {
        char* p = w + off;
        off = (off + bytes + 255) & ~(size_t)255;
        return p;
    };
    // decide eterm mode from ws_size (constant per session -> same work every call)
    size_t fixed = (size_t)NN*HID*4*2 + (size_t)NN*HEADS*4*2 + (size_t)NN*4*3
                 + (size_t)ETOT*4*2 + 16384;
    bool multi = (ws_size >= fixed + (size_t)LAYERS * ETOT * HEADS * 4 + 65536);
    int nl = multi ? LAYERS : 1;

    float* hA      = (float*)alloc((size_t)NN * HID * 4);
    float* xh      = (float*)alloc((size_t)NN * HID * 4);
    float* asrc    = (float*)alloc((size_t)NN * HEADS * 4);
    float* adst    = (float*)alloc((size_t)NN * HEADS * 4);
    int*   counts  = (int*)  alloc((size_t)NN * 4);
    int*   offsets = (int*)  alloc((size_t)NN * 4);
    int*   fill    = (int*)  alloc((size_t)NN * 4);
    int*   epos    = (int*)  alloc((size_t)ETOT * 4);
    int*   src_p   = (int*)  alloc((size_t)ETOT * 4);
    float* w_e     = (float*)alloc((size_t)LAYERS * EDIM * HEADS * 4);
    float* mean_s  = (float*)alloc(EDIM * 4);
    float* mean_al = (float*)alloc(LAYERS * HEADS * 4);
    float* eterm   = (float*)alloc((size_t)nl * ETOT * HEADS * 4);

    // ---- zero the accumulators ----
    hipMemsetAsync(mean_s, 0, EDIM * 4, stream);
    hipMemsetAsync(counts, 0, (size_t)NN * 4, stream);
    hipMemsetAsync(fill,   0, (size_t)NN * 4, stream);

    // ---- one-time prep ----
    mean_ea_kernel<<<256, 256, 0, stream>>>(ea, mean_s);
    precompute_kernel<<<LAYERS, 64, 0, stream>>>(lin_eW, att_edge, mean_s, w_e, mean_al);
    proj_kernel<<<NN, HID, 0, stream>>>(x, proj_W, proj_b, hA);

    int eblocks = (ETOT + 255) / 256;
    hist_kernel<<<eblocks, 256, 0, stream>>>(ei, counts);
    scan_kernel<<<1, 1024, 0, stream>>>(counts, offsets);
    scatter_kernel<<<eblocks, 256, 0, stream>>>(ei, offsets, fill, epos, src_p);
    if (multi)
        eterm_kernel<<<eblocks, 256, 0, stream>>>(ea, w_e, mean_al, epos, eterm, LAYERS);

    // ---- 3 GAT layers, ping-pong hA <-> d_out h-region ----
    const float* hin = hA;
    float* hout = out;
    for (int l = 0; l < LAYERS; l++) {
        xh_kernel<<<512, 256, 0, stream>>>(hin, lin_W + (size_t)l * HID * HID,
                                           att_src + (size_t)l * HID,
                                           att_dst + (size_t)l * HID,
                                           xh, asrc, adst);
        if (!multi)
            eterm_kernel<<<eblocks, 256, 0, stream>>>(ea, w_e + (size_t)l * EDIM * HEADS,
                                                      mean_al + (size_t)l * HEADS,
                                                      epos, eterm, 1);
        const float* et_l = multi ? (eterm + (size_t)l * ETOT * HEADS) : eterm;
        aggregate_kernel<<<(NN + 3) / 4, 256, 0, stream>>>(src_p, offsets, counts,
                                                           et_l, asrc, adst, xh, hin,
                                                           conv_bias + (size_t)l * HID,
                                                           ln_g + (size_t)l * HID,
                                                           ln_b + (size_t)l * HID, hout);
        const float* tmp = hin;
        hin = hout;
        hout = (float*)tmp;
    }
    // final h is in the d_out h-region

    // ---- fused pool + heads ----
    head_kernel<<<BGR, 512, 0, stream>>>(out, batch, sc_W1, sc_b1, sc_W2, sc_b2,
                                         nav_W1, nav_b1, nav_W2, nav_b2, out);
}

// Round 8
// 776.962 us; speedup vs baseline: 2.5380x; 1.1470x over previous
//
#include <hip/hip_runtime.h>
#include <hip/hip_bf16.h>

// Problem constants (from reference)
constexpr int NN   = 50000;    // nodes
constexpr int NE   = 800000;   // edges (without self loops)
constexpr int ETOT = NE + NN;  // edges + self loops
constexpr int BGR  = 64;       // graphs
constexpr int HID  = 128;
constexpr int HEADS= 4;
constexpr int CDIM = 32;
constexpr int EDIM = 16;
constexpr int NDIM = 8;
constexpr int LAYERS = 3;
constexpr int HALF = 64;       // HID/2
constexpr int NCLS = 6;
constexpr int NAVD = 4;

// d_out layout (flat f32): h[NN*HID], scene[BGR*NCLS], nav[BGR*NAVD], graph[BGR*HID]
constexpr int OUT_SCENE = NN * HID;
constexpr int OUT_NAV   = OUT_SCENE + BGR*NCLS;
constexpr int OUT_GRAPH = OUT_NAV + BGR*NAVD;

// NOTE: macro params must not be named x/y/z/w — they'd substitute into member accessors.
#define FMA4(Wv, Sv, Cv) { (Cv).x = fmaf((Wv).x, (Sv), (Cv).x); (Cv).y = fmaf((Wv).y, (Sv), (Cv).y); \
                           (Cv).z = fmaf((Wv).z, (Sv), (Cv).z); (Cv).w = fmaf((Wv).w, (Sv), (Cv).w); }

// ---------------- mean of edge_attr (sums; divided later) ----------------
__global__ void mean_ea_kernel(const float* __restrict__ ea, float* __restrict__ mean_sum) {
    __shared__ float sdata[256];
    int tid = threadIdx.x;
    float acc = 0.f;
    int stride = gridDim.x * blockDim.x;            // multiple of 16
    for (int i = blockIdx.x * blockDim.x + tid; i < NE * EDIM; i += stride)
        acc += ea[i];
    sdata[tid] = acc;
    __syncthreads();
    for (int off = 128; off >= 16; off >>= 1) {
        if (tid < off) sdata[tid] += sdata[tid + off];
        __syncthreads();
    }
    if (tid < 16) atomicAdd(&mean_sum[tid], sdata[tid]);
}

// ---------------- per-layer folded edge-attention matrix ----------------
__global__ void precompute_kernel(const float* __restrict__ lin_edge_W,
                                  const float* __restrict__ att_edge,
                                  const float* __restrict__ mean_sum,
                                  float* __restrict__ w_e, float* __restrict__ mean_alpha) {
    int l = blockIdx.x;
    int t = threadIdx.x;   // 64 threads
    __shared__ float we_s[EDIM * HEADS];
    const float* We = lin_edge_W + l * EDIM * HID;
    const float* ae = att_edge   + l * HEADS * CDIM;
    if (t < EDIM) {
        #pragma unroll
        for (int h = 0; h < HEADS; h++) {
            float s = 0.f;
            #pragma unroll
            for (int c = 0; c < CDIM; c++)
                s += We[t * HID + h * CDIM + c] * ae[h * CDIM + c];
            we_s[t * HEADS + h] = s;
            w_e[(l * EDIM + t) * HEADS + h] = s;
        }
    }
    __syncthreads();
    if (t < HEADS) {
        float s = 0.f;
        #pragma unroll
        for (int k = 0; k < EDIM; k++)
            s += (mean_sum[k] * (1.f / (float)NE)) * we_s[k * HEADS + t];
        mean_alpha[l * HEADS + t] = s;
    }
}

// ---------------- initial projection: h = relu(x @ proj_W + proj_b) ----------------
__global__ void proj_kernel(const float* __restrict__ x, const float* __restrict__ pW,
                            const float* __restrict__ pb, float* __restrict__ h) {
    int node = blockIdx.x;
    int t = threadIdx.x;   // 128
    __shared__ float xr[NDIM];
    if (t < NDIM) xr[t] = x[node * NDIM + t];
    __syncthreads();
    float acc = pb[t];
    #pragma unroll
    for (int k = 0; k < NDIM; k++) acc += xr[k] * pW[k * HID + t];
    h[node * HID + t] = fmaxf(acc, 0.f);
}

// ---------------- xh = h @ W ; bf16 out ; a_src/a_dst via shfl ----------------
// Block 1024 = 16 waves; W[k][c] staged in 64KB LDS.
// Thread: cslot = t&31 -> channels c0=cslot*4 ; grp = t>>5 -> 8 nodes.
// Per block-iter: 32 grps * 8 nodes = 256 nodes.
__global__ __launch_bounds__(1024)
void xh_kernel(const float* __restrict__ hin, const float* __restrict__ W,
               const float* __restrict__ As, const float* __restrict__ Ad,
               __hip_bfloat16* __restrict__ xhb, float* __restrict__ asrc,
               float* __restrict__ adst) {
    __shared__ float Ws[HID * HID];          // 64 KB, [k][c]
    {
        const float4* Wv = (const float4*)W;
        float4* Wsv = (float4*)Ws;
        #pragma unroll
        for (int i = 0; i < 4; i++)
            Wsv[i * 1024 + threadIdx.x] = Wv[i * 1024 + threadIdx.x];
    }
    __syncthreads();
    const float4* Ws4 = (const float4*)Ws;   // Ws4[k*32 + cslot]
    int t = threadIdx.x;
    int cslot = t & 31;
    int c0 = cslot * 4;
    int grp = t >> 5;                        // 0..31
    int hd = cslot >> 3;                     // head of the 4-channel slice
    float4 As4 = *(const float4*)(As + c0);
    float4 Ad4 = *(const float4*)(Ad + c0);

    for (int base = blockIdx.x * 256; base < NN; base += gridDim.x * 256) {
        int n0 = base + grp * 8;
        const float* hj[8];
        #pragma unroll
        for (int j = 0; j < 8; j++) {
            int nj = n0 + j;
            if (nj >= NN) nj = NN - 1;       // clamp (loads only)
            hj[j] = hin + (size_t)nj * HID;
        }
        float4 acc[8];
        #pragma unroll
        for (int j = 0; j < 8; j++) acc[j] = make_float4(0.f, 0.f, 0.f, 0.f);

        #pragma unroll 2
        for (int k = 0; k < HID; k += 4) {
            float4 w0 = Ws4[(k + 0) * 32 + cslot];
            float4 w1 = Ws4[(k + 1) * 32 + cslot];
            float4 w2 = Ws4[(k + 2) * 32 + cslot];
            float4 w3 = Ws4[(k + 3) * 32 + cslot];
            #pragma unroll
            for (int j = 0; j < 8; j++) {
                float4 h4 = *(const float4*)(hj[j] + k);
                FMA4(w0, h4.x, acc[j]);
                FMA4(w1, h4.y, acc[j]);
                FMA4(w2, h4.z, acc[j]);
                FMA4(w3, h4.w, acc[j]);
            }
        }

        #pragma unroll
        for (int j = 0; j < 8; j++) {
            int n = n0 + j;
            bool ok = (n < NN);
            // pack 4 channels to bf16 (8B store)
            union { ushort4 u4; __hip_bfloat16 b[4]; } pk;
            pk.b[0] = __float2bfloat16(acc[j].x);
            pk.b[1] = __float2bfloat16(acc[j].y);
            pk.b[2] = __float2bfloat16(acc[j].z);
            pk.b[3] = __float2bfloat16(acc[j].w);
            if (ok) *(ushort4*)(xhb + (size_t)n * HID + c0) = pk.u4;
            // attention dots: sum over the 8 cslots of this head (lanes xor 1,2,4)
            float rs = acc[j].x * As4.x + acc[j].y * As4.y + acc[j].z * As4.z + acc[j].w * As4.w;
            float rd = acc[j].x * Ad4.x + acc[j].y * Ad4.y + acc[j].z * Ad4.z + acc[j].w * Ad4.w;
            rs += __shfl_xor(rs, 1); rd += __shfl_xor(rd, 1);
            rs += __shfl_xor(rs, 2); rd += __shfl_xor(rd, 2);
            rs += __shfl_xor(rs, 4); rd += __shfl_xor(rd, 4);
            if (ok && (t & 7) == 0) {
                asrc[n * HEADS + hd] = rs;
                adst[n * HEADS + hd] = rd;
            }
        }
    }
}

// ---------------- CSR build ----------------
__global__ void hist_kernel(const int* __restrict__ ei, int* __restrict__ counts) {
    int e = blockIdx.x * blockDim.x + threadIdx.x;
    if (e >= ETOT) return;
    int d = (e < NE) ? ei[NE + e] : (e - NE);
    atomicAdd(&counts[d], 1);
}

// single-block shfl-based exclusive scan of counts -> offsets
__global__ void scan_kernel(const int* __restrict__ counts, int* __restrict__ offsets) {
    __shared__ int wsum[16];
    __shared__ int carry_s;
    int lane = threadIdx.x & 63;
    int wid  = threadIdx.x >> 6;
    if (threadIdx.x == 0) carry_s = 0;
    __syncthreads();
    for (int base = 0; base < NN; base += 1024) {
        int i = base + threadIdx.x;
        int v = (i < NN) ? counts[i] : 0;
        int x = v;
        #pragma unroll
        for (int off = 1; off < 64; off <<= 1) {
            int y = __shfl_up(x, off);
            if (lane >= off) x += y;
        }
        if (lane == 63) wsum[wid] = x;
        __syncthreads();
        if (wid == 0) {
            int w = (lane < 16) ? wsum[lane] : 0;
            #pragma unroll
            for (int off = 1; off < 16; off <<= 1) {
                int y = __shfl_up(w, off);
                if (lane >= off) w += y;
            }
            if (lane < 16) wsum[lane] = w;   // inclusive scan of wave sums
        }
        __syncthreads();
        int waveoff = (wid == 0) ? 0 : wsum[wid - 1];
        int carry = carry_s;
        if (i < NN) offsets[i] = carry + waveoff + x - v;   // exclusive
        __syncthreads();
        if (threadIdx.x == 0) carry_s = carry + wsum[15];
        __syncthreads();
    }
}

// scatter: record inverse permutation epos[e] and CSR-ordered source node ids
__global__ void scatter_kernel(const int* __restrict__ ei, const int* __restrict__ offsets,
                               int* __restrict__ fill, int* __restrict__ epos,
                               int* __restrict__ src_p) {
    int e = blockIdx.x * blockDim.x + threadIdx.x;
    if (e >= ETOT) return;
    int s, d;
    if (e < NE) { s = ei[e]; d = ei[NE + e]; }
    else        { s = d = e - NE; }
    int pos = offsets[d] + atomicAdd(&fill[d], 1);
    epos[e]   = pos;
    src_p[pos] = s;
}

// ---------------- raw edge attention terms (ea @ w_e), CSR order, nl layers ----------------
__global__ void eterm_kernel(const float* __restrict__ ea,
                             const float* __restrict__ w_e, const float* __restrict__ mean_alpha,
                             const int* __restrict__ epos, float* __restrict__ dst, int nl) {
    __shared__ float we_s[LAYERS * EDIM * HEADS];
    __shared__ float ma_s[LAYERS * HEADS];
    if (threadIdx.x < nl * EDIM * HEADS) we_s[threadIdx.x] = w_e[threadIdx.x];
    if (threadIdx.x < nl * HEADS) ma_s[threadIdx.x] = mean_alpha[threadIdx.x];
    __syncthreads();
    int e = blockIdx.x * blockDim.x + threadIdx.x;
    if (e >= ETOT) return;
    int pos = epos[e];
    if (e < NE) {
        float er[EDIM];
        const float4* ev = (const float4*)(ea + (size_t)e * EDIM);
        float4 v0 = ev[0], v1 = ev[1], v2 = ev[2], v3 = ev[3];
        er[0]=v0.x; er[1]=v0.y; er[2]=v0.z; er[3]=v0.w;
        er[4]=v1.x; er[5]=v1.y; er[6]=v1.z; er[7]=v1.w;
        er[8]=v2.x; er[9]=v2.y; er[10]=v2.z; er[11]=v2.w;
        er[12]=v3.x; er[13]=v3.y; er[14]=v3.z; er[15]=v3.w;
        for (int l = 0; l < nl; l++) {
            float e0 = 0.f, e1 = 0.f, e2 = 0.f, e3 = 0.f;
            const float* ws = we_s + l * EDIM * HEADS;
            #pragma unroll
            for (int k = 0; k < EDIM; k++) {
                float xv = er[k];
                e0 += xv * ws[k * HEADS + 0];
                e1 += xv * ws[k * HEADS + 1];
                e2 += xv * ws[k * HEADS + 2];
                e3 += xv * ws[k * HEADS + 3];
            }
            *(float4*)(dst + (size_t)l * ETOT * HEADS + (size_t)pos * HEADS)
                = make_float4(e0, e1, e2, e3);
        }
    } else {
        for (int l = 0; l < nl; l++) {
            *(float4*)(dst + (size_t)l * ETOT * HEADS + (size_t)pos * HEADS)
                = make_float4(ma_s[l*HEADS+0], ma_s[l*HEADS+1], ma_s[l*HEADS+2], ma_s[l*HEADS+3]);
        }
    }
}

// ---------------- per-node aggregation (inline alpha + online softmax) + LN ----------------
// One 64-lane wave per node; lane owns channels 2*lane, 2*lane+1; head = lane>>4.
__launch_bounds__(256)
__global__ void aggregate_kernel(const int* __restrict__ src_p, const int* __restrict__ offsets,
                                 const int* __restrict__ counts,
                                 const float* __restrict__ eterm,
                                 const float* __restrict__ asrc, const float* __restrict__ adst,
                                 const __hip_bfloat16* __restrict__ xhb,
                                 const float* __restrict__ hres, const float* __restrict__ bias,
                                 const float* __restrict__ lng, const float* __restrict__ lnb,
                                 float* __restrict__ hout) {
    int wid  = threadIdx.x >> 6;
    int lane = threadIdx.x & 63;
    int node = blockIdx.x * 4 + wid;
    if (node >= NN) return;
    int start = offsets[node];
    int deg   = counts[node];
    int head  = lane >> 4;
    int c0    = lane * 2;
    float ad_h = adst[node * HEADS + head];

    float m = -1e30f, dsum = 0.f, acc0 = 0.f, acc1 = 0.f;
    int j = 0;
    for (; j + 3 < deg; j += 4) {
        int p0 = start + j, p1 = p0 + 1, p2 = p0 + 2, p3 = p0 + 3;
        int s0 = src_p[p0], s1 = src_p[p1], s2 = src_p[p2], s3 = src_p[p3];
        float a0 = asrc[s0 * HEADS + head] + ad_h + eterm[(size_t)p0 * HEADS + head];
        float a1 = asrc[s1 * HEADS + head] + ad_h + eterm[(size_t)p1 * HEADS + head];
        float a2 = asrc[s2 * HEADS + head] + ad_h + eterm[(size_t)p2 * HEADS + head];
        float a3 = asrc[s3 * HEADS + head] + ad_h + eterm[(size_t)p3 * HEADS + head];
        a0 = (a0 > 0.f) ? a0 : 0.2f * a0;
        a1 = (a1 > 0.f) ? a1 : 0.2f * a1;
        a2 = (a2 > 0.f) ? a2 : 0.2f * a2;
        a3 = (a3 > 0.f) ? a3 : 0.2f * a3;
        __hip_bfloat162 b0 = *(const __hip_bfloat162*)(xhb + (size_t)s0 * HID + c0);
        __hip_bfloat162 b1 = *(const __hip_bfloat162*)(xhb + (size_t)s1 * HID + c0);
        __hip_bfloat162 b2 = *(const __hip_bfloat162*)(xhb + (size_t)s2 * HID + c0);
        __hip_bfloat162 b3 = *(const __hip_bfloat162*)(xhb + (size_t)s3 * HID + c0);
        float mn = fmaxf(m, fmaxf(fmaxf(a0, a1), fmaxf(a2, a3)));
        float sc = __expf(m - mn);
        float q0 = __expf(a0 - mn), q1 = __expf(a1 - mn);
        float q2 = __expf(a2 - mn), q3 = __expf(a3 - mn);
        dsum = fmaf(dsum, sc, (q0 + q1) + (q2 + q3));
        acc0 = fmaf(acc0, sc, fmaf(q0, __bfloat162float(b0.x),
                     fmaf(q1, __bfloat162float(b1.x),
                     fmaf(q2, __bfloat162float(b2.x), q3 * __bfloat162float(b3.x)))));
        acc1 = fmaf(acc1, sc, fmaf(q0, __bfloat162float(b0.y),
                     fmaf(q1, __bfloat162float(b1.y),
                     fmaf(q2, __bfloat162float(b2.y), q3 * __bfloat162float(b3.y)))));
        m = mn;
    }
    for (; j < deg; j++) {
        int pi = start + j;
        int s0 = src_p[pi];
        float a0 = asrc[s0 * HEADS + head] + ad_h + eterm[(size_t)pi * HEADS + head];
        a0 = (a0 > 0.f) ? a0 : 0.2f * a0;
        __hip_bfloat162 b0 = *(const __hip_bfloat162*)(xhb + (size_t)s0 * HID + c0);
        float mn = fmaxf(m, a0);
        float sc = __expf(m - mn);
        float q0 = __expf(a0 - mn);
        dsum = fmaf(dsum, sc, q0);
        acc0 = fmaf(acc0, sc, q0 * __bfloat162float(b0.x));
        acc1 = fmaf(acc1, sc, q0 * __bfloat162float(b0.y));
        m = mn;
    }
    float inv = 1.f / (dsum + 1e-16f);
    float2 r = *(const float2*)(hres + (size_t)node * HID + c0);
    float v0 = acc0 * inv + bias[c0]     + r.x;
    float v1 = acc1 * inv + bias[c0 + 1] + r.y;

    // LayerNorm over 128 channels spread 2-per-lane across the wave
    float ssum = v0 + v1;
    #pragma unroll
    for (int off = 32; off > 0; off >>= 1) ssum += __shfl_xor(ssum, off);
    float mu = ssum * (1.f / 128.f);
    float d0 = v0 - mu, d1 = v1 - mu;
    float vs = d0 * d0 + d1 * d1;
    #pragma unroll
    for (int off = 32; off > 0; off >>= 1) vs += __shfl_xor(vs, off);
    float rstd = rsqrtf(vs * (1.f / 128.f) + 1e-5f);
    float y0 = fmaxf(d0 * rstd * lng[c0]     + lnb[c0],     0.f);
    float y1 = fmaxf(d1 * rstd * lng[c0 + 1] + lnb[c0 + 1], 0.f);
    *(float2*)(hout + (size_t)node * HID + c0) = make_float2(y0, y1);
}

// ---------------- fused pool (sorted batch -> contiguous ranges) + heads ----------------
__launch_bounds__(512)
__global__ void head_kernel(const float* __restrict__ h, const int* __restrict__ batch,
                            const float* __restrict__ scW1, const float* __restrict__ scb1,
                            const float* __restrict__ scW2, const float* __restrict__ scb2,
                            const float* __restrict__ nvW1, const float* __restrict__ nvb1,
                            const float* __restrict__ nvW2, const float* __restrict__ nvb2,
                            float* __restrict__ out) {
    int b = blockIdx.x;
    int t = threadIdx.x;   // 512
    __shared__ float part[4][HID];
    __shared__ float gr[HID];
    __shared__ float h1[HALF];
    __shared__ float h2[HALF];
    int lo = 0, hi = NN;
    while (lo < hi) { int mid = (lo + hi) >> 1; if (batch[mid] < b) lo = mid + 1; else hi = mid; }
    int s0 = lo;
    lo = s0; hi = NN;
    while (lo < hi) { int mid = (lo + hi) >> 1; if (batch[mid] < b + 1) lo = mid + 1; else hi = mid; }
    int e0 = lo;
    int cnt = e0 - s0;

    int r  = t >> 7;      // 0..3
    int ch = t & 127;
    float acc = 0.f;
    for (int i = s0 + r; i < e0; i += 4) acc += h[(size_t)i * HID + ch];
    part[r][ch] = acc;
    __syncthreads();
    if (t < HID) {
        float g = (part[0][t] + part[1][t] + part[2][t] + part[3][t]) / fmaxf((float)cnt, 1.f);
        gr[t] = g;
        out[OUT_GRAPH + b * HID + t] = g;
    }
    __syncthreads();
    if (t < HALF) {
        float a = scb1[t], n = nvb1[t];
        #pragma unroll 4
        for (int k = 0; k < HID; k++) {
            float g = gr[k];
            a += g * scW1[k * HALF + t];
            n += g * nvW1[k * HALF + t];
        }
        h1[t] = fmaxf(a, 0.f);
        h2[t] = fmaxf(n, 0.f);
    }
    __syncthreads();
    if (t < NCLS) {
        float a = scb2[t];
        #pragma unroll 8
        for (int j = 0; j < HALF; j++) a += h1[j] * scW2[j * NCLS + t];
        out[OUT_SCENE + b * NCLS + t] = a;
    }
    if (t >= 64 && t < 64 + NAVD) {
        int q = t - 64;
        float a = nvb2[q];
        #pragma unroll 8
        for (int j = 0; j < HALF; j++) a += h2[j] * nvW2[j * NAVD + q];
        out[OUT_NAV + b * NAVD + q] = 1.f / (1.f + expf(-a));
    }
}

extern "C" void kernel_launch(void* const* d_in, const int* in_sizes, int n_in,
                              void* d_out, int out_size, void* d_ws, size_t ws_size,
                              hipStream_t stream) {
    const float* x        = (const float*)d_in[0];
    const int*   ei       = (const int*)  d_in[1];
    const float* ea       = (const float*)d_in[2];
    const int*   batch    = (const int*)  d_in[3];
    const float* proj_W   = (const float*)d_in[4];
    const float* proj_b   = (const float*)d_in[5];
    const float* lin_W    = (const float*)d_in[6];
    const float* lin_eW   = (const float*)d_in[7];
    const float* att_src  = (const float*)d_in[8];
    const float* att_dst  = (const float*)d_in[9];
    const float* att_edge = (const float*)d_in[10];
    const float* conv_bias= (const float*)d_in[11];
    const float* ln_g     = (const float*)d_in[12];
    const float* ln_b     = (const float*)d_in[13];
    const float* sc_W1    = (const float*)d_in[14];
    const float* sc_b1    = (const float*)d_in[15];
    const float* sc_W2    = (const float*)d_in[16];
    const float* sc_b2    = (const float*)d_in[17];
    const float* nav_W1   = (const float*)d_in[18];
    const float* nav_b1   = (const float*)d_in[19];
    const float* nav_W2   = (const float*)d_in[20];
    const float* nav_b2   = (const float*)d_in[21];
    float* out = (float*)d_out;

    // ---- workspace carve-up (256B aligned regions) ----
    char* w = (char*)d_ws;
    size_t off = 0;
    auto alloc = [&](size_t bytes) -> char* {
        char* p = w + off;
        off = (off + bytes + 255) & ~(size_t)255;
        return p;
    };
    // decide eterm mode from ws_size (constant per session -> same work every call)
    size_t fixed = (size_t)NN*HID*4 + (size_t)NN*HID*2 + (size_t)NN*HEADS*4*2 + (size_t)NN*4*3
                 + (size_t)ETOT*4*2 + 16384;
    bool multi = (ws_size >= fixed + (size_t)LAYERS * ETOT * HEADS * 4 + 65536);
    int nl = multi ? LAYERS : 1;

    float* hA              = (float*)alloc((size_t)NN * HID * 4);
    __hip_bfloat16* xhb    = (__hip_bfloat16*)alloc((size_t)NN * HID * 2);
    float* asrc    = (float*)alloc((size_t)NN * HEADS * 4);
    float* adst    = (float*)alloc((size_t)NN * HEADS * 4);
    int*   counts  = (int*)  alloc((size_t)NN * 4);
    int*   offsets = (int*)  alloc((size_t)NN * 4);
    int*   fill    = (int*)  alloc((size_t)NN * 4);
    int*   epos    = (int*)  alloc((size_t)ETOT * 4);
    int*   src_p   = (int*)  alloc((size_t)ETOT * 4);
    float* w_e     = (float*)alloc((size_t)LAYERS * EDIM * HEADS * 4);
    float* mean_s  = (float*)alloc(EDIM * 4);
    float* mean_al = (float*)alloc(LAYERS * HEADS * 4);
    float* eterm   = (float*)alloc((size_t)nl * ETOT * HEADS * 4);

    // ---- zero the accumulators ----
    (void)hipMemsetAsync(mean_s, 0, EDIM * 4, stream);
    (void)hipMemsetAsync(counts, 0, (size_t)NN * 4, stream);
    (void)hipMemsetAsync(fill,   0, (size_t)NN * 4, stream);

    // ---- one-time prep ----
    mean_ea_kernel<<<256, 256, 0, stream>>>(ea, mean_s);
    precompute_kernel<<<LAYERS, 64, 0, stream>>>(lin_eW, att_edge, mean_s, w_e, mean_al);
    proj_kernel<<<NN, HID, 0, stream>>>(x, proj_W, proj_b, hA);

    int eblocks = (ETOT + 255) / 256;
    hist_kernel<<<eblocks, 256, 0, stream>>>(ei, counts);
    scan_kernel<<<1, 1024, 0, stream>>>(counts, offsets);
    scatter_kernel<<<eblocks, 256, 0, stream>>>(ei, offsets, fill, epos, src_p);
    if (multi)
        eterm_kernel<<<eblocks, 256, 0, stream>>>(ea, w_e, mean_al, epos, eterm, LAYERS);

    // ---- 3 GAT layers, ping-pong hA <-> d_out h-region ----
    int xblocks = (NN + 255) / 256;   // 196
    const float* hin = hA;
    float* hout = out;
    for (int l = 0; l < LAYERS; l++) {
        xh_kernel<<<xblocks, 1024, 0, stream>>>(hin, lin_W + (size_t)l * HID * HID,
                                                att_src + (size_t)l * HID,
                                                att_dst + (size_t)l * HID,
                                                xhb, asrc, adst);
        if (!multi)
            eterm_kernel<<<eblocks, 256, 0, stream>>>(ea, w_e + (size_t)l * EDIM * HEADS,
                                                      mean_al + (size_t)l * HEADS,
                                                      epos, eterm, 1);
        const float* et_l = multi ? (eterm + (size_t)l * ETOT * HEADS) : eterm;
        aggregate_kernel<<<(NN + 3) / 4, 256, 0, stream>>>(src_p, offsets, counts,
                                                           et_l, asrc, adst, xhb, hin,
                                                           conv_bias + (size_t)l * HID,
                                                           ln_g + (size_t)l * HID,
                                                           ln_b + (size_t)l * HID, hout);
        const float* tmp = hin;
        hin = hout;
        hout = (float*)tmp;
    }
    // final h is in the d_out h-region

    // ---- fused pool + heads ----
    head_kernel<<<BGR, 512, 0, stream>>>(out, batch, sc_W1, sc_b1, sc_W2, sc_b2,
                                         nav_W1, nav_b1, nav_W2, nav_b2, out);
}

// Round 10
// 728.370 us; speedup vs baseline: 2.7073x; 1.0667x over previous
//
#include <hip/hip_runtime.h>
#include <hip/hip_bf16.h>

// Problem constants (from reference)
constexpr int NN   = 50000;    // nodes
constexpr int NE   = 800000;   // edges (without self loops)
constexpr int ETOT = NE + NN;  // edges + self loops
constexpr int BGR  = 64;       // graphs
constexpr int HID  = 128;
constexpr int HEADS= 4;
constexpr int CDIM = 32;
constexpr int EDIM = 16;
constexpr int NDIM = 8;
constexpr int LAYERS = 3;
constexpr int HALF = 64;       // HID/2
constexpr int NCLS = 6;
constexpr int NAVD = 4;
constexpr int PB   = 8;        // pool partial blocks per graph
constexpr int MEANBLK = 1024;  // mean_ea4 grid

// d_out layout (flat f32): h[NN*HID], scene[BGR*NCLS], nav[BGR*NAVD], graph[BGR*HID]
constexpr int OUT_SCENE = NN * HID;
constexpr int OUT_NAV   = OUT_SCENE + BGR*NCLS;
constexpr int OUT_GRAPH = OUT_NAV + BGR*NAVD;

// NOTE: macro params must not be named x/y/z/w — they'd substitute into member accessors.
#define FMA4(Wv, Sv, Cv) { (Cv).x = fmaf((Wv).x, (Sv), (Cv).x); (Cv).y = fmaf((Wv).y, (Sv), (Cv).y); \
                           (Cv).z = fmaf((Wv).z, (Sv), (Cv).z); (Cv).w = fmaf((Wv).w, (Sv), (Cv).w); }

// ---------------- mean of edge_attr: stage 1, per-block partial sums ----------------
// float4 loads; thread t's channel group g = t&3 (channels 4g..4g+3) is invariant
// because all strides are multiples of 4 float4s.
__global__ __launch_bounds__(256)
void mean_ea4_kernel(const float* __restrict__ ea, float* __restrict__ partials) {
    const float4* ea4 = (const float4*)ea;
    constexpr int TOT4 = NE * EDIM / 4;      // 3.2M
    int t = threadIdx.x;
    float ax = 0.f, ay = 0.f, az = 0.f, aw = 0.f;
    for (int i = blockIdx.x * 256 + t; i < TOT4; i += gridDim.x * 256) {
        float4 v = ea4[i];
        ax += v.x; ay += v.y; az += v.z; aw += v.w;
    }
    __shared__ float s[256][4];
    s[t][0] = ax; s[t][1] = ay; s[t][2] = az; s[t][3] = aw;
    __syncthreads();
    // reduce threads with equal t&3 (offsets are multiples of 4)
    for (int off = 128; off >= 4; off >>= 1) {
        if (t < off) {
            s[t][0] += s[t + off][0]; s[t][1] += s[t + off][1];
            s[t][2] += s[t + off][2]; s[t][3] += s[t + off][3];
        }
        __syncthreads();
    }
    if (t < 4) {   // group t -> channels 4t..4t+3
        partials[blockIdx.x * EDIM + 4 * t + 0] = s[t][0];
        partials[blockIdx.x * EDIM + 4 * t + 1] = s[t][1];
        partials[blockIdx.x * EDIM + 4 * t + 2] = s[t][2];
        partials[blockIdx.x * EDIM + 4 * t + 3] = s[t][3];
    }
}

// stage 2: reduce MEANBLK partial rows -> mean_sum[16]
__global__ void mean_reduce_kernel(const float* __restrict__ partials,
                                   float* __restrict__ mean_sum) {
    __shared__ float s[256];
    int t = threadIdx.x;          // 256
    int ch = t & 15, grp = t >> 4;   // 16 groups
    float acc = 0.f;
    for (int j = grp; j < MEANBLK; j += 16) acc += partials[j * EDIM + ch];
    s[t] = acc;
    __syncthreads();
    if (t < 16) {
        float a = 0.f;
        #pragma unroll
        for (int g = 0; g < 16; g++) a += s[g * 16 + t];
        mean_sum[t] = a;
    }
}

// ---------------- per-layer folded edge-attention matrix ----------------
__global__ void precompute_kernel(const float* __restrict__ lin_edge_W,
                                  const float* __restrict__ att_edge,
                                  const float* __restrict__ mean_sum,
                                  float* __restrict__ w_e, float* __restrict__ mean_alpha) {
    int l = blockIdx.x;
    int t = threadIdx.x;   // 64 threads
    __shared__ float we_s[EDIM * HEADS];
    const float* We = lin_edge_W + l * EDIM * HID;
    const float* ae = att_edge   + l * HEADS * CDIM;
    if (t < EDIM) {
        #pragma unroll
        for (int h = 0; h < HEADS; h++) {
            float s = 0.f;
            #pragma unroll
            for (int c = 0; c < CDIM; c++)
                s += We[t * HID + h * CDIM + c] * ae[h * CDIM + c];
            we_s[t * HEADS + h] = s;
            w_e[(l * EDIM + t) * HEADS + h] = s;
        }
    }
    __syncthreads();
    if (t < HEADS) {
        float s = 0.f;
        #pragma unroll
        for (int k = 0; k < EDIM; k++)
            s += (mean_sum[k] * (1.f / (float)NE)) * we_s[k * HEADS + t];
        mean_alpha[l * HEADS + t] = s;
    }
}

// ---------------- initial projection: h = relu(x @ proj_W + proj_b) ----------------
__global__ void proj_kernel(const float* __restrict__ x, const float* __restrict__ pW,
                            const float* __restrict__ pb, float* __restrict__ h) {
    int node = blockIdx.x;
    int t = threadIdx.x;   // 128
    __shared__ float xr[NDIM];
    if (t < NDIM) xr[t] = x[node * NDIM + t];
    __syncthreads();
    float acc = pb[t];
    #pragma unroll
    for (int k = 0; k < NDIM; k++) acc += xr[k] * pW[k * HID + t];
    h[node * HID + t] = fmaxf(acc, 0.f);
}

// ---------------- xh = h @ W ; bf16 out ; a_src/a_dst via shfl ----------------
// Block 1024 = 16 waves; W[k][c] staged in 64KB LDS.
__global__ __launch_bounds__(1024)
void xh_kernel(const float* __restrict__ hin, const float* __restrict__ W,
               const float* __restrict__ As, const float* __restrict__ Ad,
               __hip_bfloat16* __restrict__ xhb, float* __restrict__ asrc,
               float* __restrict__ adst) {
    __shared__ float Ws[HID * HID];          // 64 KB, [k][c]
    {
        const float4* Wv = (const float4*)W;
        float4* Wsv = (float4*)Ws;
        #pragma unroll
        for (int i = 0; i < 4; i++)
            Wsv[i * 1024 + threadIdx.x] = Wv[i * 1024 + threadIdx.x];
    }
    __syncthreads();
    const float4* Ws4 = (const float4*)Ws;   // Ws4[k*32 + cslot]
    int t = threadIdx.x;
    int cslot = t & 31;
    int c0 = cslot * 4;
    int grp = t >> 5;                        // 0..31
    int hd = cslot >> 3;                     // head of the 4-channel slice
    float4 As4 = *(const float4*)(As + c0);
    float4 Ad4 = *(const float4*)(Ad + c0);

    for (int base = blockIdx.x * 256; base < NN; base += gridDim.x * 256) {
        int n0 = base + grp * 8;
        const float* hj[8];
        #pragma unroll
        for (int j = 0; j < 8; j++) {
            int nj = n0 + j;
            if (nj >= NN) nj = NN - 1;       // clamp (loads only)
            hj[j] = hin + (size_t)nj * HID;
        }
        float4 acc[8];
        #pragma unroll
        for (int j = 0; j < 8; j++) acc[j] = make_float4(0.f, 0.f, 0.f, 0.f);

        #pragma unroll 2
        for (int k = 0; k < HID; k += 4) {
            float4 w0 = Ws4[(k + 0) * 32 + cslot];
            float4 w1 = Ws4[(k + 1) * 32 + cslot];
            float4 w2 = Ws4[(k + 2) * 32 + cslot];
            float4 w3 = Ws4[(k + 3) * 32 + cslot];
            #pragma unroll
            for (int j = 0; j < 8; j++) {
                float4 h4 = *(const float4*)(hj[j] + k);
                FMA4(w0, h4.x, acc[j]);
                FMA4(w1, h4.y, acc[j]);
                FMA4(w2, h4.z, acc[j]);
                FMA4(w3, h4.w, acc[j]);
            }
        }

        #pragma unroll
        for (int j = 0; j < 8; j++) {
            int n = n0 + j;
            bool ok = (n < NN);
            union { ushort4 u4; __hip_bfloat16 b[4]; } pk;
            pk.b[0] = __float2bfloat16(acc[j].x);
            pk.b[1] = __float2bfloat16(acc[j].y);
            pk.b[2] = __float2bfloat16(acc[j].z);
            pk.b[3] = __float2bfloat16(acc[j].w);
            if (ok) *(ushort4*)(xhb + (size_t)n * HID + c0) = pk.u4;
            float rs = acc[j].x * As4.x + acc[j].y * As4.y + acc[j].z * As4.z + acc[j].w * As4.w;
            float rd = acc[j].x * Ad4.x + acc[j].y * Ad4.y + acc[j].z * Ad4.z + acc[j].w * Ad4.w;
            rs += __shfl_xor(rs, 1); rd += __shfl_xor(rd, 1);
            rs += __shfl_xor(rs, 2); rd += __shfl_xor(rd, 2);
            rs += __shfl_xor(rs, 4); rd += __shfl_xor(rd, 4);
            if (ok && (t & 7) == 0) {
                asrc[n * HEADS + hd] = rs;
                adst[n * HEADS + hd] = rd;
            }
        }
    }
}

// ---------------- CSR build ----------------
__global__ void hist_kernel(const int* __restrict__ ei, int* __restrict__ counts) {
    int e = blockIdx.x * blockDim.x + threadIdx.x;
    if (e >= ETOT) return;
    int d = (e < NE) ? ei[NE + e] : (e - NE);
    atomicAdd(&counts[d], 1);
}

// single-block shfl-based exclusive scan of counts -> offsets
__global__ void scan_kernel(const int* __restrict__ counts, int* __restrict__ offsets) {
    __shared__ int wsum[16];
    __shared__ int carry_s;
    int lane = threadIdx.x & 63;
    int wid  = threadIdx.x >> 6;
    if (threadIdx.x == 0) carry_s = 0;
    __syncthreads();
    for (int base = 0; base < NN; base += 1024) {
        int i = base + threadIdx.x;
        int v = (i < NN) ? counts[i] : 0;
        int x = v;
        #pragma unroll
        for (int off = 1; off < 64; off <<= 1) {
            int y = __shfl_up(x, off);
            if (lane >= off) x += y;
        }
        if (lane == 63) wsum[wid] = x;
        __syncthreads();
        if (wid == 0) {
            int w = (lane < 16) ? wsum[lane] : 0;
            #pragma unroll
            for (int off = 1; off < 16; off <<= 1) {
                int y = __shfl_up(w, off);
                if (lane >= off) w += y;
            }
            if (lane < 16) wsum[lane] = w;   // inclusive scan of wave sums
        }
        __syncthreads();
        int waveoff = (wid == 0) ? 0 : wsum[wid - 1];
        int carry = carry_s;
        if (i < NN) offsets[i] = carry + waveoff + x - v;   // exclusive
        __syncthreads();
        if (threadIdx.x == 0) carry_s = carry + wsum[15];
        __syncthreads();
    }
}

// scatter: record inverse permutation epos[e] and CSR-ordered source node ids
__global__ void scatter_kernel(const int* __restrict__ ei, const int* __restrict__ offsets,
                               int* __restrict__ fill, int* __restrict__ epos,
                               int* __restrict__ src_p) {
    int e = blockIdx.x * blockDim.x + threadIdx.x;
    if (e >= ETOT) return;
    int s, d;
    if (e < NE) { s = ei[e]; d = ei[NE + e]; }
    else        { s = d = e - NE; }
    int pos = offsets[d] + atomicAdd(&fill[d], 1);
    epos[e]   = pos;
    src_p[pos] = s;
}

// ---------------- raw edge attention terms (ea @ w_e), CSR order, nl layers ----------------
__global__ void eterm_kernel(const float* __restrict__ ea,
                             const float* __restrict__ w_e, const float* __restrict__ mean_alpha,
                             const int* __restrict__ epos, float* __restrict__ dst, int nl) {
    __shared__ float we_s[LAYERS * EDIM * HEADS];
    __shared__ float ma_s[LAYERS * HEADS];
    if (threadIdx.x < nl * EDIM * HEADS) we_s[threadIdx.x] = w_e[threadIdx.x];
    if (threadIdx.x < nl * HEADS) ma_s[threadIdx.x] = mean_alpha[threadIdx.x];
    __syncthreads();
    int e = blockIdx.x * blockDim.x + threadIdx.x;
    if (e >= ETOT) return;
    int pos = epos[e];
    if (e < NE) {
        float er[EDIM];
        const float4* ev = (const float4*)(ea + (size_t)e * EDIM);
        float4 v0 = ev[0], v1 = ev[1], v2 = ev[2], v3 = ev[3];
        er[0]=v0.x; er[1]=v0.y; er[2]=v0.z; er[3]=v0.w;
        er[4]=v1.x; er[5]=v1.y; er[6]=v1.z; er[7]=v1.w;
        er[8]=v2.x; er[9]=v2.y; er[10]=v2.z; er[11]=v2.w;
        er[12]=v3.x; er[13]=v3.y; er[14]=v3.z; er[15]=v3.w;
        for (int l = 0; l < nl; l++) {
            float e0 = 0.f, e1 = 0.f, e2 = 0.f, e3 = 0.f;
            const float* ws = we_s + l * EDIM * HEADS;
            #pragma unroll
            for (int k = 0; k < EDIM; k++) {
                float xv = er[k];
                e0 += xv * ws[k * HEADS + 0];
                e1 += xv * ws[k * HEADS + 1];
                e2 += xv * ws[k * HEADS + 2];
                e3 += xv * ws[k * HEADS + 3];
            }
            *(float4*)(dst + (size_t)l * ETOT * HEADS + (size_t)pos * HEADS)
                = make_float4(e0, e1, e2, e3);
        }
    } else {
        for (int l = 0; l < nl; l++) {
            *(float4*)(dst + (size_t)l * ETOT * HEADS + (size_t)pos * HEADS)
                = make_float4(ma_s[l*HEADS+0], ma_s[l*HEADS+1], ma_s[l*HEADS+2], ma_s[l*HEADS+3]);
        }
    }
}

// ---------------- per-node aggregation (inline alpha + online softmax) + LN ----------------
__launch_bounds__(256)
__global__ void aggregate_kernel(const int* __restrict__ src_p, const int* __restrict__ offsets,
                                 const int* __restrict__ counts,
                                 const float* __restrict__ eterm,
                                 const float* __restrict__ asrc, const float* __restrict__ adst,
                                 const __hip_bfloat16* __restrict__ xhb,
                                 const float* __restrict__ hres, const float* __restrict__ bias,
                                 const float* __restrict__ lng, const float* __restrict__ lnb,
                                 float* __restrict__ hout) {
    int wid  = threadIdx.x >> 6;
    int lane = threadIdx.x & 63;
    int node = blockIdx.x * 4 + wid;
    if (node >= NN) return;
    int start = offsets[node];
    int deg   = counts[node];
    int head  = lane >> 4;
    int c0    = lane * 2;
    float ad_h = adst[node * HEADS + head];

    float m = -1e30f, dsum = 0.f, acc0 = 0.f, acc1 = 0.f;
    int j = 0;
    for (; j + 3 < deg; j += 4) {
        int p0 = start + j, p1 = p0 + 1, p2 = p0 + 2, p3 = p0 + 3;
        int s0 = src_p[p0], s1 = src_p[p1], s2 = src_p[p2], s3 = src_p[p3];
        float a0 = asrc[s0 * HEADS + head] + ad_h + eterm[(size_t)p0 * HEADS + head];
        float a1 = asrc[s1 * HEADS + head] + ad_h + eterm[(size_t)p1 * HEADS + head];
        float a2 = asrc[s2 * HEADS + head] + ad_h + eterm[(size_t)p2 * HEADS + head];
        float a3 = asrc[s3 * HEADS + head] + ad_h + eterm[(size_t)p3 * HEADS + head];
        a0 = (a0 > 0.f) ? a0 : 0.2f * a0;
        a1 = (a1 > 0.f) ? a1 : 0.2f * a1;
        a2 = (a2 > 0.f) ? a2 : 0.2f * a2;
        a3 = (a3 > 0.f) ? a3 : 0.2f * a3;
        __hip_bfloat162 b0 = *(const __hip_bfloat162*)(xhb + (size_t)s0 * HID + c0);
        __hip_bfloat162 b1 = *(const __hip_bfloat162*)(xhb + (size_t)s1 * HID + c0);
        __hip_bfloat162 b2 = *(const __hip_bfloat162*)(xhb + (size_t)s2 * HID + c0);
        __hip_bfloat162 b3 = *(const __hip_bfloat162*)(xhb + (size_t)s3 * HID + c0);
        float mn = fmaxf(m, fmaxf(fmaxf(a0, a1), fmaxf(a2, a3)));
        float sc = __expf(m - mn);
        float q0 = __expf(a0 - mn), q1 = __expf(a1 - mn);
        float q2 = __expf(a2 - mn), q3 = __expf(a3 - mn);
        dsum = fmaf(dsum, sc, (q0 + q1) + (q2 + q3));
        acc0 = fmaf(acc0, sc, fmaf(q0, __bfloat162float(b0.x),
                     fmaf(q1, __bfloat162float(b1.x),
                     fmaf(q2, __bfloat162float(b2.x), q3 * __bfloat162float(b3.x)))));
        acc1 = fmaf(acc1, sc, fmaf(q0, __bfloat162float(b0.y),
                     fmaf(q1, __bfloat162float(b1.y),
                     fmaf(q2, __bfloat162float(b2.y), q3 * __bfloat162float(b3.y)))));
        m = mn;
    }
    for (; j < deg; j++) {
        int pi = start + j;
        int s0 = src_p[pi];
        float a0 = asrc[s0 * HEADS + head] + ad_h + eterm[(size_t)pi * HEADS + head];
        a0 = (a0 > 0.f) ? a0 : 0.2f * a0;
        __hip_bfloat162 b0 = *(const __hip_bfloat162*)(xhb + (size_t)s0 * HID + c0);
        float mn = fmaxf(m, a0);
        float sc = __expf(m - mn);
        float q0 = __expf(a0 - mn);
        dsum = fmaf(dsum, sc, q0);
        acc0 = fmaf(acc0, sc, q0 * __bfloat162float(b0.x));
        acc1 = fmaf(acc1, sc, q0 * __bfloat162float(b0.y));
        m = mn;
    }
    float inv = 1.f / (dsum + 1e-16f);
    float2 r = *(const float2*)(hres + (size_t)node * HID + c0);
    float v0 = acc0 * inv + bias[c0]     + r.x;
    float v1 = acc1 * inv + bias[c0 + 1] + r.y;

    float ssum = v0 + v1;
    #pragma unroll
    for (int off = 32; off > 0; off >>= 1) ssum += __shfl_xor(ssum, off);
    float mu = ssum * (1.f / 128.f);
    float d0 = v0 - mu, d1 = v1 - mu;
    float vs = d0 * d0 + d1 * d1;
    #pragma unroll
    for (int off = 32; off > 0; off >>= 1) vs += __shfl_xor(vs, off);
    float rstd = rsqrtf(vs * (1.f / 128.f) + 1e-5f);
    float y0 = fmaxf(d0 * rstd * lng[c0]     + lnb[c0],     0.f);
    float y1 = fmaxf(d1 * rstd * lng[c0 + 1] + lnb[c0 + 1], 0.f);
    *(float2*)(hout + (size_t)node * HID + c0) = make_float2(y0, y1);
}

// ---------------- pool stage 1: per-(graph, slice) partial sums ----------------
// grid = BGR * PB blocks, 128 threads (one per channel)
__global__ __launch_bounds__(128)
void pool_partial_kernel(const float* __restrict__ h, const int* __restrict__ batch,
                         float* __restrict__ pp) {
    int b = blockIdx.x >> 3;     // graph
    int r = blockIdx.x & (PB - 1);
    int ch = threadIdx.x;        // 0..127
    int lo = 0, hi = NN;
    while (lo < hi) { int mid = (lo + hi) >> 1; if (batch[mid] < b) lo = mid + 1; else hi = mid; }
    int s0 = lo;
    lo = s0; hi = NN;
    while (lo < hi) { int mid = (lo + hi) >> 1; if (batch[mid] < b + 1) lo = mid + 1; else hi = mid; }
    int e0 = lo;
    float acc = 0.f;
    for (int i = s0 + r; i < e0; i += PB) acc += h[(size_t)i * HID + ch];
    pp[(size_t)(b * PB + r) * HID + ch] = acc;
}

// ---------------- pool stage 2 + heads (128 threads/graph) ----------------
__launch_bounds__(128)
__global__ void head_kernel(const float* __restrict__ pp, const int* __restrict__ batch,
                            const float* __restrict__ scW1, const float* __restrict__ scb1,
                            const float* __restrict__ scW2, const float* __restrict__ scb2,
                            const float* __restrict__ nvW1, const float* __restrict__ nvb1,
                            const float* __restrict__ nvW2, const float* __restrict__ nvb2,
                            float* __restrict__ out) {
    int b = blockIdx.x;
    int t = threadIdx.x;   // 128
    __shared__ float gr[HID];
    __shared__ float h1[HALF];
    __shared__ float h2[HALF];
    int lo = 0, hi = NN;
    while (lo < hi) { int mid = (lo + hi) >> 1; if (batch[mid] < b) lo = mid + 1; else hi = mid; }
    int s0 = lo;
    lo = s0; hi = NN;
    while (lo < hi) { int mid = (lo + hi) >> 1; if (batch[mid] < b + 1) lo = mid + 1; else hi = mid; }
    int cnt = lo - s0;

    float g = 0.f;
    #pragma unroll
    for (int r = 0; r < PB; r++) g += pp[(size_t)(b * PB + r) * HID + t];
    g /= fmaxf((float)cnt, 1.f);
    gr[t] = g;
    out[OUT_GRAPH + b * HID + t] = g;
    __syncthreads();
    if (t < HALF) {
        float a = scb1[t], n = nvb1[t];
        #pragma unroll 4
        for (int k = 0; k < HID; k++) {
            float gv = gr[k];
            a += gv * scW1[k * HALF + t];
            n += gv * nvW1[k * HALF + t];
        }
        h1[t] = fmaxf(a, 0.f);
        h2[t] = fmaxf(n, 0.f);
    }
    __syncthreads();
    if (t < NCLS) {
        float a = scb2[t];
        #pragma unroll 8
        for (int j = 0; j < HALF; j++) a += h1[j] * scW2[j * NCLS + t];
        out[OUT_SCENE + b * NCLS + t] = a;
    }
    if (t >= 64 && t < 64 + NAVD) {
        int q = t - 64;
        float a = nvb2[q];
        #pragma unroll 8
        for (int j = 0; j < HALF; j++) a += h2[j] * nvW2[j * NAVD + q];
        out[OUT_NAV + b * NAVD + q] = 1.f / (1.f + expf(-a));
    }
}

extern "C" void kernel_launch(void* const* d_in, const int* in_sizes, int n_in,
                              void* d_out, int out_size, void* d_ws, size_t ws_size,
                              hipStream_t stream) {
    const float* x        = (const float*)d_in[0];
    const int*   ei       = (const int*)  d_in[1];
    const float* ea       = (const float*)d_in[2];
    const int*   batch    = (const int*)  d_in[3];
    const float* proj_W   = (const float*)d_in[4];
    const float* proj_b   = (const float*)d_in[5];
    const float* lin_W    = (const float*)d_in[6];
    const float* lin_eW   = (const float*)d_in[7];
    const float* att_src  = (const float*)d_in[8];
    const float* att_dst  = (const float*)d_in[9];
    const float* att_edge = (const float*)d_in[10];
    const float* conv_bias= (const float*)d_in[11];
    const float* ln_g     = (const float*)d_in[12];
    const float* ln_b     = (const float*)d_in[13];
    const float* sc_W1    = (const float*)d_in[14];
    const float* sc_b1    = (const float*)d_in[15];
    const float* sc_W2    = (const float*)d_in[16];
    const float* sc_b2    = (const float*)d_in[17];
    const float* nav_W1   = (const float*)d_in[18];
    const float* nav_b1   = (const float*)d_in[19];
    const float* nav_W2   = (const float*)d_in[20];
    const float* nav_b2   = (const float*)d_in[21];
    float* out = (float*)d_out;

    // ---- workspace carve-up (256B aligned regions) ----
    char* w = (char*)d_ws;
    size_t off = 0;
    auto alloc = [&](size_t bytes) -> char* {
        char* p = w + off;
        off = (off + bytes + 255) & ~(size_t)255;
        return p;
    };
    // decide eterm mode from ws_size (constant per session -> same work every call)
    size_t fixed = (size_t)NN*HID*4 + (size_t)NN*HID*2 + (size_t)NN*HEADS*4*2 + (size_t)NN*4*3
                 + (size_t)ETOT*4*2 + (size_t)MEANBLK*EDIM*4 + (size_t)BGR*PB*HID*4 + 32768;
    bool multi = (ws_size >= fixed + (size_t)LAYERS * ETOT * HEADS * 4 + 65536);
    int nl = multi ? LAYERS : 1;

    float* hA              = (float*)alloc((size_t)NN * HID * 4);
    __hip_bfloat16* xhb    = (__hip_bfloat16*)alloc((size_t)NN * HID * 2);
    float* asrc    = (float*)alloc((size_t)NN * HEADS * 4);
    float* adst    = (float*)alloc((size_t)NN * HEADS * 4);
    int*   counts  = (int*)  alloc((size_t)NN * 4);
    int*   offsets = (int*)  alloc((size_t)NN * 4);
    int*   fill    = (int*)  alloc((size_t)NN * 4);
    int*   epos    = (int*)  alloc((size_t)ETOT * 4);
    int*   src_p   = (int*)  alloc((size_t)ETOT * 4);
    float* w_e     = (float*)alloc((size_t)LAYERS * EDIM * HEADS * 4);
    float* mean_p  = (float*)alloc((size_t)MEANBLK * EDIM * 4);
    float* mean_s  = (float*)alloc(EDIM * 4);
    float* mean_al = (float*)alloc(LAYERS * HEADS * 4);
    float* poolp   = (float*)alloc((size_t)BGR * PB * HID * 4);
    float* eterm   = (float*)alloc((size_t)nl * ETOT * HEADS * 4);

    // ---- zero the accumulators ----
    (void)hipMemsetAsync(counts, 0, (size_t)NN * 4, stream);
    (void)hipMemsetAsync(fill,   0, (size_t)NN * 4, stream);

    // ---- one-time prep ----
    mean_ea4_kernel<<<MEANBLK, 256, 0, stream>>>(ea, mean_p);
    mean_reduce_kernel<<<1, 256, 0, stream>>>(mean_p, mean_s);
    precompute_kernel<<<LAYERS, 64, 0, stream>>>(lin_eW, att_edge, mean_s, w_e, mean_al);
    proj_kernel<<<NN, HID, 0, stream>>>(x, proj_W, proj_b, hA);

    int eblocks = (ETOT + 255) / 256;
    hist_kernel<<<eblocks, 256, 0, stream>>>(ei, counts);
    scan_kernel<<<1, 1024, 0, stream>>>(counts, offsets);
    scatter_kernel<<<eblocks, 256, 0, stream>>>(ei, offsets, fill, epos, src_p);
    if (multi)
        eterm_kernel<<<eblocks, 256, 0, stream>>>(ea, w_e, mean_al, epos, eterm, LAYERS);

    // ---- 3 GAT layers, ping-pong hA <-> d_out h-region ----
    int xblocks = (NN + 255) / 256;   // 196
    const float* hin = hA;
    float* hout = out;
    for (int l = 0; l < LAYERS; l++) {
        xh_kernel<<<xblocks, 1024, 0, stream>>>(hin, lin_W + (size_t)l * HID * HID,
                                                att_src + (size_t)l * HID,
                                                att_dst + (size_t)l * HID,
                                                xhb, asrc, adst);
        if (!multi)
            eterm_kernel<<<eblocks, 256, 0, stream>>>(ea, w_e + (size_t)l * EDIM * HEADS,
                                                      mean_al + (size_t)l * HEADS,
                                                      epos, eterm, 1);
        const float* et_l = multi ? (eterm + (size_t)l * ETOT * HEADS) : eterm;
        aggregate_kernel<<<(NN + 3) / 4, 256, 0, stream>>>(src_p, offsets, counts,
                                                           et_l, asrc, adst, xhb, hin,
                                                           conv_bias + (size_t)l * HID,
                                                           ln_g + (size_t)l * HID,
                                                           ln_b + (size_t)l * HID, hout);
        const float* tmp = hin;
        hin = hout;
        hout = (float*)tmp;
    }
    // final h is in the d_out h-region

    // ---- two-stage pool + heads ----
    pool_partial_kernel<<<BGR * PB, 128, 0, stream>>>(out, batch, poolp);
    head_kernel<<<BGR, 128, 0, stream>>>(poolp, batch, sc_W1, sc_b1, sc_W2, sc_b2,
                                         nav_W1, nav_b1, nav_W2, nav_b2, out);
}